// Round 8
// baseline (307.347 us; speedup 1.0000x reference)
//
#include <hip/hip_runtime.h>
#include <hip/hip_bf16.h>
#include <math.h>

typedef __attribute__((ext_vector_type(8))) __bf16 bf16x8;
typedef __attribute__((ext_vector_type(4))) __bf16 bf16x4;
typedef __attribute__((ext_vector_type(4))) float f32x4;
typedef __attribute__((ext_vector_type(4))) short short4_t;

#define D_MODEL 1024
#define SEQ     2048
#define BATCH   4
#define NH      16
#define HD      64
#define MROWS   (BATCH * SEQ)   // 8192

// 0.125 (1/sqrt(64)) * log2(e): folded into Q at the QKV-GEMM epilogue
#define SCALE_LOG2E 0.18033688011112042f

__device__ __forceinline__ void gld_lds16(const __bf16* g, __bf16* l) {
  __builtin_amdgcn_global_load_lds(
      (const __attribute__((address_space(1))) void*)g,
      (__attribute__((address_space(3))) void*)l, 16, 0, 0);
}

// ---------------- convert x: fp32 -> bf16, vectorized ----------------
__global__ __launch_bounds__(256) void cvt_x(const float* __restrict__ in,
                                             __bf16* __restrict__ out) {
  int i = (blockIdx.x * 256 + threadIdx.x) * 4;
  float4 f = *(const float4*)(in + i);
  bf16x4 o;
  o.x = (__bf16)f.x; o.y = (__bf16)f.y; o.z = (__bf16)f.z; o.w = (__bf16)f.w;
  *(bf16x4*)(out + i) = o;
}

// -- convert + transpose weights: fp32 [K][N] -> bf16 [N][K], all 4 in one
// dispatch (blockIdx.z selects the weight; saves 3 launch overheads) --
__global__ __launch_bounds__(256) void cvt_wt4(const float* __restrict__ W0,
                                               const float* __restrict__ W1,
                                               const float* __restrict__ W2,
                                               const float* __restrict__ W3,
                                               __bf16* __restrict__ Wqkv,
                                               __bf16* __restrict__ Wot) {
  __shared__ __bf16 t[32][33];
  int tx = threadIdx.x, ty = threadIdx.y;   // block (32,8)
  int z = blockIdx.z;
  const float* W = (z == 0) ? W0 : (z == 1) ? W1 : (z == 2) ? W2 : W3;
  __bf16* Wt = (z < 3) ? (Wqkv + (size_t)z * 1024 * 1024) : Wot;
  int n0 = blockIdx.x * 32, k0 = blockIdx.y * 32;
#pragma unroll
  for (int j = 0; j < 32; j += 8)
    t[ty + j][tx] = (__bf16)W[(size_t)(k0 + ty + j) * D_MODEL + n0 + tx];
  __syncthreads();
#pragma unroll
  for (int j = 0; j < 32; j += 8)
    Wt[(size_t)(n0 + ty + j) * D_MODEL + k0 + tx] = t[tx][ty + j];
}

// ---------------- GEMM: C[M,N] = A[M,K] @ Bt[N,K]^T  (bf16, m97 structure)
// R0 structure EXACTLY: single-buffer LDS, 2 barriers/K-step, 16 KB LDS ->
// ~4 blocks/CU. R1-R3 showed every intra-block pipelining variant loses to
// this at K=1024: inter-BLOCK overlap from high occupancy beats intra-block
// scheduling, and bigger LDS cuts blocks/CU (m132 lesson).
// Operand-swap trick: passing (Bfrag, Afrag) to MFMA yields C^T tiles, so a
// lane holds 4 CONSECUTIVE minor-dim outputs -> vector stores (b64/b128)
// instead of 4 scalar stores. Orientation chosen per output layout:
// EPI 0 (SWAP): QK, N=2048. lane: token=l16, d=quad*4+i -> bf16x4 to [b,h,n,d]
//               (which = Q or K per 1024-col block; Q pre-scaled)
// EPI 1 (no swap): V, N=1024. lane: d=l16, token=quad*4+i -> bf16x4 to [b,h,d,n]
// EPI 2 (SWAP): proj, N=1024 fp32. lane: row=l16, col=quad*4+i -> float4+bias
template <int EPI>
__global__ __launch_bounds__(256) void gemm_bt(const __bf16* __restrict__ A,
                                               const __bf16* __restrict__ Bt,
                                               const float* __restrict__ bias,
                                               void* __restrict__ Cout) {
  constexpr int Kd = 1024;
  constexpr bool SWAP = (EPI != 1);
  __shared__ __bf16 As[128 * 32];
  __shared__ __bf16 Bs[128 * 32];
  const int tid = threadIdx.x;
  const int lane = tid & 63;
  const int w = tid >> 6;
  const int quad = lane >> 4, l16 = lane & 15;
  const int wr = w >> 1, wc = w & 1;
  const int tm = blockIdx.y * 128, tn = blockIdx.x * 128;

  f32x4 acc[4][4] = {};

  const int u0 = (w * 2) * 64 + lane;
  const int u1 = u0 + 64;
  const int rA0 = u0 >> 2, kofs0 = (u0 & 3) * 8;
  const int rA1 = u1 >> 2, kofs1 = (u1 & 3) * 8;
  const __bf16* gA0 = A + (size_t)(tm + rA0) * Kd + kofs0;
  const __bf16* gA1 = A + (size_t)(tm + rA1) * Kd + kofs1;
  const __bf16* gB0 = Bt + (size_t)(tn + rA0) * Kd + kofs0;
  const __bf16* gB1 = Bt + (size_t)(tn + rA1) * Kd + kofs1;
  __bf16* lA0 = As + (w * 2 + 0) * 512;
  __bf16* lA1 = As + (w * 2 + 1) * 512;
  __bf16* lB0 = Bs + (w * 2 + 0) * 512;
  __bf16* lB1 = Bs + (w * 2 + 1) * 512;

  for (int k0 = 0; k0 < Kd; k0 += 32) {
    gld_lds16(gA0 + k0, lA0);
    gld_lds16(gA1 + k0, lA1);
    gld_lds16(gB0 + k0, lB0);
    gld_lds16(gB1 + k0, lB1);
    __syncthreads();
    bf16x8 af[4], bfr[4];
#pragma unroll
    for (int t = 0; t < 4; ++t) {
      af[t]  = *(const bf16x8*)&As[(wr * 64 + t * 16 + l16) * 32 + quad * 8];
      bfr[t] = *(const bf16x8*)&Bs[(wc * 64 + t * 16 + l16) * 32 + quad * 8];
    }
#pragma unroll
    for (int mt = 0; mt < 4; ++mt)
#pragma unroll
      for (int nt = 0; nt < 4; ++nt) {
        if constexpr (SWAP)
          acc[mt][nt] = __builtin_amdgcn_mfma_f32_16x16x32_bf16(
              bfr[nt], af[mt], acc[mt][nt], 0, 0, 0);
        else
          acc[mt][nt] = __builtin_amdgcn_mfma_f32_16x16x32_bf16(
              af[mt], bfr[nt], acc[mt][nt], 0, 0, 0);
      }
    __syncthreads();
  }

#pragma unroll
  for (int mt = 0; mt < 4; ++mt)
#pragma unroll
    for (int nt = 0; nt < 4; ++nt) {
      if constexpr (EPI == 2) {
        // C^T tile: row of D = out col, col of D = out row (token)
        int gm  = tm + wr * 64 + mt * 16 + l16;        // token
        int gn0 = tn + wc * 64 + nt * 16 + quad * 4;   // col base
        float4 bv = *(const float4*)&bias[gn0];
        float4 o;
        o.x = acc[mt][nt][0] + bv.x;
        o.y = acc[mt][nt][1] + bv.y;
        o.z = acc[mt][nt][2] + bv.z;
        o.w = acc[mt][nt][3] + bv.w;
        *(float4*)&((float*)Cout)[(size_t)gm * 1024 + gn0] = o;
      } else if constexpr (EPI == 0) {
        int gm = tm + wr * 64 + mt * 16 + l16;         // token
        int f0 = tn + wc * 64 + nt * 16 + quad * 4;    // 0..2047 (Q|K)
        int which = f0 >> 10, col = f0 & 1023;
        int b = gm >> 11, nn = gm & 2047, h = col >> 6, d = col & 63;
        float s = (which == 0) ? SCALE_LOG2E : 1.0f;
        bf16x4 o;
        o[0] = (__bf16)(acc[mt][nt][0] * s);
        o[1] = (__bf16)(acc[mt][nt][1] * s);
        o[2] = (__bf16)(acc[mt][nt][2] * s);
        o[3] = (__bf16)(acc[mt][nt][3] * s);
        __bf16* op = (__bf16*)Cout + (size_t)which * (BATCH * SEQ * (size_t)D_MODEL) +
                     ((size_t)(b * NH + h) * SEQ + nn) * HD + d;
        *(bf16x4*)op = o;
      } else {   // EPI 1: V transposed, natural orientation
        int gm0 = tm + wr * 64 + mt * 16 + quad * 4;   // token base
        int gn  = tn + wc * 64 + nt * 16 + l16;        // feature 0..1023
        int b = gm0 >> 11, nn0 = gm0 & 2047, h = gn >> 6, d = gn & 63;
        bf16x4 o;
        o[0] = (__bf16)acc[mt][nt][0];
        o[1] = (__bf16)acc[mt][nt][1];
        o[2] = (__bf16)acc[mt][nt][2];
        o[3] = (__bf16)acc[mt][nt][3];
        __bf16* op = (__bf16*)Cout + ((size_t)(b * NH + h) * HD + d) * SEQ + nn0;
        *(bf16x4*)op = o;
      }
    }
}

// ---------------- causal flash attention, register-PV, double-buffered ----
// R6: grid (64, 16), block 256 (4 waves) -- ONE q-tile (128 rows) per block.
// R5's pairing gave 512 blocks = exactly 2 blocks/CU; occupancy (18.5%) was
// grid-capped, leaving the per-iter barrier drain uncovered (MfmaUtil 30 +
// VALUBusy 46 = ~24% idle). Halving block granularity -> 1024 blocks =
// 4 blocks/CU (16 waves/CU); per-block state also halves (single phase) so
// VGPR fits the 128 cap for 4 waves/SIMD (__launch_bounds__(256,4)).
// XCD map preserved: linear id = bx + 64*by, 64%8==0 -> xcd = bh%8: all 16
// tiles of a bh share one XCD's L2 (R5's verified 4.5x FETCH win).
// Tile order interleaves heavy/light (by odd -> 15-by/2) so co-dispatched
// chunks carry balanced work. Staging iters/bh rise 200->272; that stream is
// L2-resident (R5: 24.6 MB FETCH), ~2 us of L2 traffic for 2x hiding.
// S^T = mfma_16x16x32(Kfrag, Qfrag): lane holds S[q=l16][k=quad*4+i] -- this
// is EXACTLY the A-operand layout of mfma_f32_16x16x16_bf16 (k=quad*4+j), so
// PV runs straight from registers: no P LDS round-trip at all.
// V staged with XOR swizzle (unit = d*8 + ((k>>3)^(d&7))) so the b64 B-frag
// reads are bank-conflict-free. K/V double-buffered: 1 barrier/iter,
// prefetch of iter+1 overlaps compute of iter.
// (R1's K-swizzle REVERTED: cut bank conflicts 4.8M->3.2M but cost ~8%.)
__global__ __launch_bounds__(256, 4) void attn(const __bf16* __restrict__ Q,
                                               const __bf16* __restrict__ K,
                                               const __bf16* __restrict__ Vt,
                                               __bf16* __restrict__ ctx) {
  const int tid = threadIdx.x;
  const int lane = tid & 63, w = tid >> 6;
  const int quad = lane >> 4, l16 = lane & 15;
  const int byy = blockIdx.y;                       // 0..15
  const int tile = (byy & 1) ? (15 - (byy >> 1)) : (byy >> 1);
  const int bh = blockIdx.x;                        // 0..63
  const __bf16* qb = Q + (size_t)bh * SEQ * HD;
  const __bf16* kb = K + (size_t)bh * SEQ * HD;
  const __bf16* vb = Vt + (size_t)bh * HD * SEQ;

  __shared__ __bf16 KsAll[2 * 4096];   // [buf][half*2048 + key*32 + d]
  __shared__ __bf16 VsAll[2 * 4096];   // [buf][d*64 + ((k>>3)^(d&7))*8 + (k&7)]

  const int qmin = tile * 128 + w * 32;

  // Q fragments (B-operand, scale pre-folded)
  bf16x8 aq[2][2];
#pragma unroll
  for (int qq = 0; qq < 2; ++qq)
#pragma unroll
    for (int kk = 0; kk < 2; ++kk)
      aq[qq][kk] = *(const bf16x8*)(qb + (size_t)(qmin + qq * 16 + l16) * HD +
                                    kk * 32 + quad * 8);

  f32x4 acc[2][4] = {};   // [qq][cd] rows q=quad*4+i, cols d=cd*16+l16
  float lsum[2] = {};     // [qq] per-lane partial for q-col = l16

  // staging decode. K: unit u -> key r=(u>>2)&63, half h=u>>8, elem e=(u&3)*8.
  // V (swizzled): unit u -> d=u>>3, kc=(u&7)^(d&7).
  const int u0 = w * 128 + lane;
  const int u1 = u0 + 64;
  const int kOffG0 = ((u0 >> 2) & 63) * HD + (u0 >> 8) * 32 + (u0 & 3) * 8;
  const int kOffG1 = ((u1 >> 2) & 63) * HD + (u1 >> 8) * 32 + (u1 & 3) * 8;
  const int vd0 = u0 >> 3, vd1 = u1 >> 3;
  const int vOffG0 = vd0 * SEQ + (((u0 & 7) ^ (vd0 & 7)) * 8);
  const int vOffG1 = vd1 * SEQ + (((u1 & 7) ^ (vd1 & 7)) * 8);

  auto stage = [&](int k0s, int bufsel) {
    __bf16* Kb = KsAll + bufsel * 4096;
    __bf16* Vb = VsAll + bufsel * 4096;
    gld_lds16(kb + (size_t)k0s * HD + kOffG0, Kb + u0 * 8);
    gld_lds16(kb + (size_t)k0s * HD + kOffG1, Kb + u1 * 8);
    gld_lds16(vb + k0s + vOffG0, Vb + u0 * 8);
    gld_lds16(vb + k0s + vOffG1, Vb + u1 * 8);
  };

  const int nIter = 2 * tile + 2;
  stage(0, 0);

  for (int it = 0; it < nIter; ++it) {
    __syncthreads();   // buf[it&1] staged; all waves done with buf[(it+1)&1]
    if (it + 1 < nIter) stage((it + 1) * 64, (it + 1) & 1);

    const int k0 = it * 64;
    if (k0 <= qmin + 31) {   // this wave still has unmasked keys here
      const __bf16* Kb = KsAll + (it & 1) * 4096;
      const __bf16* Vb = VsAll + (it & 1) * 4096;

      bf16x8 bk[4][2];          // A-operand K frags: rows = keys
#pragma unroll
      for (int kt = 0; kt < 4; ++kt)
#pragma unroll
        for (int kk = 0; kk < 2; ++kk)
          bk[kt][kk] = *(const bf16x8*)&Kb[kk * 2048 + (kt * 16 + l16) * 32 + quad * 8];

      // V B-frags for K=16 PV: vf[kt][cd] = V[k=kt*16+quad*4 ..+3][d=cd*16+l16]
      short4_t vf[4][4];
#pragma unroll
      for (int kt = 0; kt < 4; ++kt)
#pragma unroll
        for (int cd = 0; cd < 4; ++cd)
          vf[kt][cd] = *(const short4_t*)&Vb[(cd * 16 + l16) * 64 +
                                             (((kt * 2 + (quad >> 1)) ^ (l16 & 7)) * 8) +
                                             (quad & 1) * 4];

      // S^T[k][q]: rows k = k0+kt*16+quad*4+i, cols q = qmin+qq*16+l16
      f32x4 St[4][2] = {};
#pragma unroll
      for (int kt = 0; kt < 4; ++kt)
#pragma unroll
        for (int qq = 0; qq < 2; ++qq) {
          St[kt][qq] = __builtin_amdgcn_mfma_f32_16x16x32_bf16(
              bk[kt][0], aq[qq][0], St[kt][qq], 0, 0, 0);
          St[kt][qq] = __builtin_amdgcn_mfma_f32_16x16x32_bf16(
              bk[kt][1], aq[qq][1], St[kt][qq], 0, 0, 0);
        }
      const bool full = (k0 + 63 <= qmin);
#pragma unroll
      for (int kt = 0; kt < 4; ++kt)
#pragma unroll
        for (int qq = 0; qq < 2; ++qq) {
          float e0 = __builtin_amdgcn_exp2f(St[kt][qq][0]);
          float e1 = __builtin_amdgcn_exp2f(St[kt][qq][1]);
          float e2 = __builtin_amdgcn_exp2f(St[kt][qq][2]);
          float e3 = __builtin_amdgcn_exp2f(St[kt][qq][3]);
          if (!full) {
            int kg = k0 + kt * 16 + quad * 4;
            int qg = qmin + qq * 16 + l16;
            if (kg + 0 > qg) e0 = 0.f;
            if (kg + 1 > qg) e1 = 0.f;
            if (kg + 2 > qg) e2 = 0.f;
            if (kg + 3 > qg) e3 = 0.f;
          }
          lsum[qq] += (e0 + e1) + (e2 + e3);
          short4_t ap;
          ap[0] = __builtin_bit_cast(short, (__bf16)e0);
          ap[1] = __builtin_bit_cast(short, (__bf16)e1);
          ap[2] = __builtin_bit_cast(short, (__bf16)e2);
          ap[3] = __builtin_bit_cast(short, (__bf16)e3);
          // PV straight from registers: O[q][d] tiles over d
#pragma unroll
          for (int cd = 0; cd < 4; ++cd)
            acc[qq][cd] = __builtin_amdgcn_mfma_f32_16x16x16bf16_1k(
                ap, vf[kt][cd], acc[qq][cd], 0, 0, 0);
        }
    }
  }

  const int bb = bh >> 4, hh = bh & 15;
#pragma unroll
  for (int qq = 0; qq < 2; ++qq) {
    float s = lsum[qq];
    s += __shfl_xor(s, 16);
    s += __shfl_xor(s, 32);   // all lanes: total for q-col = own l16
    float rinv[4];
#pragma unroll
    for (int i = 0; i < 4; ++i)
      rinv[i] = 1.0f / __shfl(s, (lane & 48) + quad * 4 + i);
#pragma unroll
    for (int c = 0; c < 4; ++c)
#pragma unroll
      for (int i = 0; i < 4; ++i) {
        int q = qmin + qq * 16 + quad * 4 + i;
        float o = acc[qq][c][i] * rinv[i];
        ctx[((size_t)(bb * SEQ + q)) * D_MODEL + hh * HD + c * 16 + l16] = (__bf16)o;
      }
  }
}

extern "C" void kernel_launch(void* const* d_in, const int* in_sizes, int n_in,
                              void* d_out, int out_size, void* d_ws, size_t ws_size,
                              hipStream_t stream) {
  const float* x  = (const float*)d_in[0];
  const float* Wq = (const float*)d_in[1];
  const float* Wk = (const float*)d_in[2];
  const float* Wv = (const float*)d_in[3];
  const float* Wo = (const float*)d_in[4];
  const float* bo = (const float*)d_in[5];
  float* out = (float*)d_out;
  char* ws = (char*)d_ws;
  const size_t MB = 1024 * 1024;
  __bf16* xb   = (__bf16*)(ws);             // 16 MB; reused as ctx after attn
  __bf16* Wqkv = (__bf16*)(ws + 16 * MB);   // 6 MB: Wqt|Wkt|Wvt contiguous
  __bf16* Wot  = (__bf16*)(ws + 22 * MB);   // 2 MB
  __bf16* Qh   = (__bf16*)(ws + 24 * MB);   // 16 MB [b,h,n,d], pre-scaled
  __bf16* Kh   = (__bf16*)(ws + 40 * MB);   // 16 MB [b,h,n,d]
  __bf16* Vth  = (__bf16*)(ws + 56 * MB);   // 16 MB [b,h,d,n]
  __bf16* ctx  = xb;                        // alias: xb dead after QKV GEMM

  cvt_x<<<MROWS * D_MODEL / (256 * 4), 256, 0, stream>>>(x, xb);
  cvt_wt4<<<dim3(32, 32, 4), dim3(32, 8), 0, stream>>>(Wq, Wk, Wv, Wo, Wqkv, Wot);

  // QK projection (swapped-operand epilogue), then V projection (natural)
  gemm_bt<0><<<dim3(16, 64), 256, 0, stream>>>(xb, Wqkv, nullptr, Qh);
  gemm_bt<1><<<dim3(8, 64), 256, 0, stream>>>(xb, Wqkv + 2 * 1024 * 1024, nullptr, Vth);

  attn<<<dim3(64, 16), 256, 0, stream>>>(Qh, Kh, Vth, ctx);

  gemm_bt<2><<<dim3(8, 64), 256, 0, stream>>>(ctx, Wot, bo, out);
}

// Round 10
// 265.958 us; speedup vs baseline: 1.1556x; 1.1556x over previous
//
#include <hip/hip_runtime.h>
#include <hip/hip_bf16.h>
#include <math.h>

typedef __attribute__((ext_vector_type(8))) __bf16 bf16x8;
typedef __attribute__((ext_vector_type(4))) __bf16 bf16x4;
typedef __attribute__((ext_vector_type(4))) float f32x4;
typedef __attribute__((ext_vector_type(4))) short short4_t;

#define D_MODEL 1024
#define SEQ     2048
#define BATCH   4
#define NH      16
#define HD      64
#define MROWS   (BATCH * SEQ)   // 8192

// 0.125 (1/sqrt(64)) * log2(e): folded into Q at the QKV-GEMM epilogue
#define SCALE_LOG2E 0.18033688011112042f

__device__ __forceinline__ void gld_lds16(const __bf16* g, __bf16* l) {
  __builtin_amdgcn_global_load_lds(
      (const __attribute__((address_space(1))) void*)g,
      (__attribute__((address_space(3))) void*)l, 16, 0, 0);
}

// ---------------- convert x: fp32 -> bf16, vectorized ----------------
__global__ __launch_bounds__(256) void cvt_x(const float* __restrict__ in,
                                             __bf16* __restrict__ out) {
  int i = (blockIdx.x * 256 + threadIdx.x) * 4;
  float4 f = *(const float4*)(in + i);
  bf16x4 o;
  o.x = (__bf16)f.x; o.y = (__bf16)f.y; o.z = (__bf16)f.z; o.w = (__bf16)f.w;
  *(bf16x4*)(out + i) = o;
}

// -- convert + transpose weights: fp32 [K][N] -> bf16 [N][K], all 4 in one
// dispatch (blockIdx.z selects the weight; saves 3 launch overheads) --
__global__ __launch_bounds__(256) void cvt_wt4(const float* __restrict__ W0,
                                               const float* __restrict__ W1,
                                               const float* __restrict__ W2,
                                               const float* __restrict__ W3,
                                               __bf16* __restrict__ Wqkv,
                                               __bf16* __restrict__ Wot) {
  __shared__ __bf16 t[32][33];
  int tx = threadIdx.x, ty = threadIdx.y;   // block (32,8)
  int z = blockIdx.z;
  const float* W = (z == 0) ? W0 : (z == 1) ? W1 : (z == 2) ? W2 : W3;
  __bf16* Wt = (z < 3) ? (Wqkv + (size_t)z * 1024 * 1024) : Wot;
  int n0 = blockIdx.x * 32, k0 = blockIdx.y * 32;
#pragma unroll
  for (int j = 0; j < 32; j += 8)
    t[ty + j][tx] = (__bf16)W[(size_t)(k0 + ty + j) * D_MODEL + n0 + tx];
  __syncthreads();
#pragma unroll
  for (int j = 0; j < 32; j += 8)
    Wt[(size_t)(n0 + ty + j) * D_MODEL + k0 + tx] = t[tx][ty + j];
}

// ---------------- GEMM: C[M,N] = A[M,K] @ Bt[N,K]^T  (bf16, m97 structure)
// R0 structure EXACTLY: single-buffer LDS, 2 barriers/K-step, 16 KB LDS ->
// ~4 blocks/CU. R1-R3 showed every intra-block pipelining variant loses to
// this at K=1024: inter-BLOCK overlap from high occupancy beats intra-block
// scheduling, and bigger LDS cuts blocks/CU (m132 lesson).
// Operand-swap trick: passing (Bfrag, Afrag) to MFMA yields C^T tiles, so a
// lane holds 4 CONSECUTIVE minor-dim outputs -> vector stores (b64/b128)
// instead of 4 scalar stores. Orientation chosen per output layout:
// EPI 0 (SWAP): QK, N=2048. lane: token=l16, d=quad*4+i -> bf16x4 to [b,h,n,d]
//               (which = Q or K per 1024-col block; Q pre-scaled)
// EPI 1 (no swap): V, N=1024. lane: d=l16, token=quad*4+i -> bf16x4 to [b,h,d,n]
// EPI 2 (SWAP): proj, N=1024 fp32. lane: row=l16, col=quad*4+i -> float4+bias
template <int EPI>
__global__ __launch_bounds__(256) void gemm_bt(const __bf16* __restrict__ A,
                                               const __bf16* __restrict__ Bt,
                                               const float* __restrict__ bias,
                                               void* __restrict__ Cout) {
  constexpr int Kd = 1024;
  constexpr bool SWAP = (EPI != 1);
  __shared__ __bf16 As[128 * 32];
  __shared__ __bf16 Bs[128 * 32];
  const int tid = threadIdx.x;
  const int lane = tid & 63;
  const int w = tid >> 6;
  const int quad = lane >> 4, l16 = lane & 15;
  const int wr = w >> 1, wc = w & 1;
  const int tm = blockIdx.y * 128, tn = blockIdx.x * 128;

  f32x4 acc[4][4] = {};

  const int u0 = (w * 2) * 64 + lane;
  const int u1 = u0 + 64;
  const int rA0 = u0 >> 2, kofs0 = (u0 & 3) * 8;
  const int rA1 = u1 >> 2, kofs1 = (u1 & 3) * 8;
  const __bf16* gA0 = A + (size_t)(tm + rA0) * Kd + kofs0;
  const __bf16* gA1 = A + (size_t)(tm + rA1) * Kd + kofs1;
  const __bf16* gB0 = Bt + (size_t)(tn + rA0) * Kd + kofs0;
  const __bf16* gB1 = Bt + (size_t)(tn + rA1) * Kd + kofs1;
  __bf16* lA0 = As + (w * 2 + 0) * 512;
  __bf16* lA1 = As + (w * 2 + 1) * 512;
  __bf16* lB0 = Bs + (w * 2 + 0) * 512;
  __bf16* lB1 = Bs + (w * 2 + 1) * 512;

  for (int k0 = 0; k0 < Kd; k0 += 32) {
    gld_lds16(gA0 + k0, lA0);
    gld_lds16(gA1 + k0, lA1);
    gld_lds16(gB0 + k0, lB0);
    gld_lds16(gB1 + k0, lB1);
    __syncthreads();
    bf16x8 af[4], bfr[4];
#pragma unroll
    for (int t = 0; t < 4; ++t) {
      af[t]  = *(const bf16x8*)&As[(wr * 64 + t * 16 + l16) * 32 + quad * 8];
      bfr[t] = *(const bf16x8*)&Bs[(wc * 64 + t * 16 + l16) * 32 + quad * 8];
    }
#pragma unroll
    for (int mt = 0; mt < 4; ++mt)
#pragma unroll
      for (int nt = 0; nt < 4; ++nt) {
        if constexpr (SWAP)
          acc[mt][nt] = __builtin_amdgcn_mfma_f32_16x16x32_bf16(
              bfr[nt], af[mt], acc[mt][nt], 0, 0, 0);
        else
          acc[mt][nt] = __builtin_amdgcn_mfma_f32_16x16x32_bf16(
              af[mt], bfr[nt], acc[mt][nt], 0, 0, 0);
      }
    __syncthreads();
  }

#pragma unroll
  for (int mt = 0; mt < 4; ++mt)
#pragma unroll
    for (int nt = 0; nt < 4; ++nt) {
      if constexpr (EPI == 2) {
        // C^T tile: row of D = out col, col of D = out row (token)
        int gm  = tm + wr * 64 + mt * 16 + l16;        // token
        int gn0 = tn + wc * 64 + nt * 16 + quad * 4;   // col base
        float4 bv = *(const float4*)&bias[gn0];
        float4 o;
        o.x = acc[mt][nt][0] + bv.x;
        o.y = acc[mt][nt][1] + bv.y;
        o.z = acc[mt][nt][2] + bv.z;
        o.w = acc[mt][nt][3] + bv.w;
        *(float4*)&((float*)Cout)[(size_t)gm * 1024 + gn0] = o;
      } else if constexpr (EPI == 0) {
        int gm = tm + wr * 64 + mt * 16 + l16;         // token
        int f0 = tn + wc * 64 + nt * 16 + quad * 4;    // 0..2047 (Q|K)
        int which = f0 >> 10, col = f0 & 1023;
        int b = gm >> 11, nn = gm & 2047, h = col >> 6, d = col & 63;
        float s = (which == 0) ? SCALE_LOG2E : 1.0f;
        bf16x4 o;
        o[0] = (__bf16)(acc[mt][nt][0] * s);
        o[1] = (__bf16)(acc[mt][nt][1] * s);
        o[2] = (__bf16)(acc[mt][nt][2] * s);
        o[3] = (__bf16)(acc[mt][nt][3] * s);
        __bf16* op = (__bf16*)Cout + (size_t)which * (BATCH * SEQ * (size_t)D_MODEL) +
                     ((size_t)(b * NH + h) * SEQ + nn) * HD + d;
        *(bf16x4*)op = o;
      } else {   // EPI 1: V transposed, natural orientation
        int gm0 = tm + wr * 64 + mt * 16 + quad * 4;   // token base
        int gn  = tn + wc * 64 + nt * 16 + l16;        // feature 0..1023
        int b = gm0 >> 11, nn0 = gm0 & 2047, h = gn >> 6, d = gn & 63;
        bf16x4 o;
        o[0] = (__bf16)acc[mt][nt][0];
        o[1] = (__bf16)acc[mt][nt][1];
        o[2] = (__bf16)acc[mt][nt][2];
        o[3] = (__bf16)acc[mt][nt][3];
        __bf16* op = (__bf16*)Cout + ((size_t)(b * NH + h) * HD + d) * SEQ + nn0;
        *(bf16x4*)op = o;
      }
    }
}

// ---------------- causal flash attention, register-PV, double-buffered ----
// R9: grid (64, 16), block 256 (4 waves), ONE q-tile (128 rows) per block --
// R6's finer granularity KEPT, but the forced __launch_bounds__(256,4)
// REMOVED. R8 counters showed that bound made the compiler cap the unified
// VGPR+AGPR file at 128/wave (VGPR_Count 64, WRITE_SIZE 16->45 MB of scratch
// spill, dur 68->112 us). With (256,2) the compiler allocates naturally
// (~95-115 VGPR single-phase); at <=128 total the HW still co-schedules
// 4 blocks/CU -- occupancy WITHOUT spills.
// XCD map: linear id = bx + 64*by, 64%8==0 -> xcd = bh%8: all 16 tiles of a
// bh share one XCD's L2 (R5's verified 4.5x FETCH win). Tile order
// interleaves heavy/light (by odd -> 15-by/2) for dispatch balance.
// S^T = mfma_16x16x32(Kfrag, Qfrag): lane holds S[q=l16][k=quad*4+i] -- this
// is EXACTLY the A-operand layout of mfma_f32_16x16x16_bf16 (k=quad*4+j), so
// PV runs straight from registers: no P LDS round-trip at all.
// V staged with XOR swizzle (unit = d*8 + ((k>>3)^(d&7))) so the b64 B-frag
// reads are bank-conflict-free. K/V double-buffered: 1 barrier/iter,
// prefetch of iter+1 overlaps compute of iter.
// (R1's K-swizzle REVERTED: cut bank conflicts 4.8M->3.2M but cost ~8%.)
__global__ __launch_bounds__(256, 2) void attn(const __bf16* __restrict__ Q,
                                               const __bf16* __restrict__ K,
                                               const __bf16* __restrict__ Vt,
                                               __bf16* __restrict__ ctx) {
  const int tid = threadIdx.x;
  const int lane = tid & 63, w = tid >> 6;
  const int quad = lane >> 4, l16 = lane & 15;
  const int byy = blockIdx.y;                       // 0..15
  const int tile = (byy & 1) ? (15 - (byy >> 1)) : (byy >> 1);
  const int bh = blockIdx.x;                        // 0..63
  const __bf16* qb = Q + (size_t)bh * SEQ * HD;
  const __bf16* kb = K + (size_t)bh * SEQ * HD;
  const __bf16* vb = Vt + (size_t)bh * HD * SEQ;

  __shared__ __bf16 KsAll[2 * 4096];   // [buf][half*2048 + key*32 + d]
  __shared__ __bf16 VsAll[2 * 4096];   // [buf][d*64 + ((k>>3)^(d&7))*8 + (k&7)]

  const int qmin = tile * 128 + w * 32;

  // Q fragments (B-operand, scale pre-folded)
  bf16x8 aq[2][2];
#pragma unroll
  for (int qq = 0; qq < 2; ++qq)
#pragma unroll
    for (int kk = 0; kk < 2; ++kk)
      aq[qq][kk] = *(const bf16x8*)(qb + (size_t)(qmin + qq * 16 + l16) * HD +
                                    kk * 32 + quad * 8);

  f32x4 acc[2][4] = {};   // [qq][cd] rows q=quad*4+i, cols d=cd*16+l16
  float lsum[2] = {};     // [qq] per-lane partial for q-col = l16

  // staging decode. K: unit u -> key r=(u>>2)&63, half h=u>>8, elem e=(u&3)*8.
  // V (swizzled): unit u -> d=u>>3, kc=(u&7)^(d&7).
  const int u0 = w * 128 + lane;
  const int u1 = u0 + 64;
  const int kOffG0 = ((u0 >> 2) & 63) * HD + (u0 >> 8) * 32 + (u0 & 3) * 8;
  const int kOffG1 = ((u1 >> 2) & 63) * HD + (u1 >> 8) * 32 + (u1 & 3) * 8;
  const int vd0 = u0 >> 3, vd1 = u1 >> 3;
  const int vOffG0 = vd0 * SEQ + (((u0 & 7) ^ (vd0 & 7)) * 8);
  const int vOffG1 = vd1 * SEQ + (((u1 & 7) ^ (vd1 & 7)) * 8);

  auto stage = [&](int k0s, int bufsel) {
    __bf16* Kb = KsAll + bufsel * 4096;
    __bf16* Vb = VsAll + bufsel * 4096;
    gld_lds16(kb + (size_t)k0s * HD + kOffG0, Kb + u0 * 8);
    gld_lds16(kb + (size_t)k0s * HD + kOffG1, Kb + u1 * 8);
    gld_lds16(vb + k0s + vOffG0, Vb + u0 * 8);
    gld_lds16(vb + k0s + vOffG1, Vb + u1 * 8);
  };

  const int nIter = 2 * tile + 2;
  stage(0, 0);

  for (int it = 0; it < nIter; ++it) {
    __syncthreads();   // buf[it&1] staged; all waves done with buf[(it+1)&1]
    if (it + 1 < nIter) stage((it + 1) * 64, (it + 1) & 1);

    const int k0 = it * 64;
    if (k0 <= qmin + 31) {   // this wave still has unmasked keys here
      const __bf16* Kb = KsAll + (it & 1) * 4096;
      const __bf16* Vb = VsAll + (it & 1) * 4096;

      bf16x8 bk[4][2];          // A-operand K frags: rows = keys
#pragma unroll
      for (int kt = 0; kt < 4; ++kt)
#pragma unroll
        for (int kk = 0; kk < 2; ++kk)
          bk[kt][kk] = *(const bf16x8*)&Kb[kk * 2048 + (kt * 16 + l16) * 32 + quad * 8];

      // V B-frags for K=16 PV: vf[kt][cd] = V[k=kt*16+quad*4 ..+3][d=cd*16+l16]
      short4_t vf[4][4];
#pragma unroll
      for (int kt = 0; kt < 4; ++kt)
#pragma unroll
        for (int cd = 0; cd < 4; ++cd)
          vf[kt][cd] = *(const short4_t*)&Vb[(cd * 16 + l16) * 64 +
                                             (((kt * 2 + (quad >> 1)) ^ (l16 & 7)) * 8) +
                                             (quad & 1) * 4];

      // S^T[k][q]: rows k = k0+kt*16+quad*4+i, cols q = qmin+qq*16+l16
      f32x4 St[4][2] = {};
#pragma unroll
      for (int kt = 0; kt < 4; ++kt)
#pragma unroll
        for (int qq = 0; qq < 2; ++qq) {
          St[kt][qq] = __builtin_amdgcn_mfma_f32_16x16x32_bf16(
              bk[kt][0], aq[qq][0], St[kt][qq], 0, 0, 0);
          St[kt][qq] = __builtin_amdgcn_mfma_f32_16x16x32_bf16(
              bk[kt][1], aq[qq][1], St[kt][qq], 0, 0, 0);
        }
      const bool full = (k0 + 63 <= qmin);
#pragma unroll
      for (int kt = 0; kt < 4; ++kt)
#pragma unroll
        for (int qq = 0; qq < 2; ++qq) {
          float e0 = __builtin_amdgcn_exp2f(St[kt][qq][0]);
          float e1 = __builtin_amdgcn_exp2f(St[kt][qq][1]);
          float e2 = __builtin_amdgcn_exp2f(St[kt][qq][2]);
          float e3 = __builtin_amdgcn_exp2f(St[kt][qq][3]);
          if (!full) {
            int kg = k0 + kt * 16 + quad * 4;
            int qg = qmin + qq * 16 + l16;
            if (kg + 0 > qg) e0 = 0.f;
            if (kg + 1 > qg) e1 = 0.f;
            if (kg + 2 > qg) e2 = 0.f;
            if (kg + 3 > qg) e3 = 0.f;
          }
          lsum[qq] += (e0 + e1) + (e2 + e3);
          short4_t ap;
          ap[0] = __builtin_bit_cast(short, (__bf16)e0);
          ap[1] = __builtin_bit_cast(short, (__bf16)e1);
          ap[2] = __builtin_bit_cast(short, (__bf16)e2);
          ap[3] = __builtin_bit_cast(short, (__bf16)e3);
          // PV straight from registers: O[q][d] tiles over d
#pragma unroll
          for (int cd = 0; cd < 4; ++cd)
            acc[qq][cd] = __builtin_amdgcn_mfma_f32_16x16x16bf16_1k(
                ap, vf[kt][cd], acc[qq][cd], 0, 0, 0);
        }
    }
  }

  const int bb = bh >> 4, hh = bh & 15;
#pragma unroll
  for (int qq = 0; qq < 2; ++qq) {
    float s = lsum[qq];
    s += __shfl_xor(s, 16);
    s += __shfl_xor(s, 32);   // all lanes: total for q-col = own l16
    float rinv[4];
#pragma unroll
    for (int i = 0; i < 4; ++i)
      rinv[i] = 1.0f / __shfl(s, (lane & 48) + quad * 4 + i);
#pragma unroll
    for (int c = 0; c < 4; ++c)
#pragma unroll
      for (int i = 0; i < 4; ++i) {
        int q = qmin + qq * 16 + quad * 4 + i;
        float o = acc[qq][c][i] * rinv[i];
        ctx[((size_t)(bb * SEQ + q)) * D_MODEL + hh * HD + c * 16 + l16] = (__bf16)o;
      }
  }
}

extern "C" void kernel_launch(void* const* d_in, const int* in_sizes, int n_in,
                              void* d_out, int out_size, void* d_ws, size_t ws_size,
                              hipStream_t stream) {
  const float* x  = (const float*)d_in[0];
  const float* Wq = (const float*)d_in[1];
  const float* Wk = (const float*)d_in[2];
  const float* Wv = (const float*)d_in[3];
  const float* Wo = (const float*)d_in[4];
  const float* bo = (const float*)d_in[5];
  float* out = (float*)d_out;
  char* ws = (char*)d_ws;
  const size_t MB = 1024 * 1024;
  __bf16* xb   = (__bf16*)(ws);             // 16 MB; reused as ctx after attn
  __bf16* Wqkv = (__bf16*)(ws + 16 * MB);   // 6 MB: Wqt|Wkt|Wvt contiguous
  __bf16* Wot  = (__bf16*)(ws + 22 * MB);   // 2 MB
  __bf16* Qh   = (__bf16*)(ws + 24 * MB);   // 16 MB [b,h,n,d], pre-scaled
  __bf16* Kh   = (__bf16*)(ws + 40 * MB);   // 16 MB [b,h,n,d]
  __bf16* Vth  = (__bf16*)(ws + 56 * MB);   // 16 MB [b,h,d,n]
  __bf16* ctx  = xb;                        // alias: xb dead after QKV GEMM

  cvt_x<<<MROWS * D_MODEL / (256 * 4), 256, 0, stream>>>(x, xb);
  cvt_wt4<<<dim3(32, 32, 4), dim3(32, 8), 0, stream>>>(Wq, Wk, Wv, Wo, Wqkv, Wot);

  // QK projection (swapped-operand epilogue), then V projection (natural)
  gemm_bt<0><<<dim3(16, 64), 256, 0, stream>>>(xb, Wqkv, nullptr, Qh);
  gemm_bt<1><<<dim3(8, 64), 256, 0, stream>>>(xb, Wqkv + 2 * 1024 * 1024, nullptr, Vth);

  attn<<<dim3(64, 16), 256, 0, stream>>>(Qh, Kh, Vth, ctx);

  gemm_bt<2><<<dim3(8, 64), 256, 0, stream>>>(ctx, Wot, bo, out);
}

// Round 11
// 261.134 us; speedup vs baseline: 1.1770x; 1.0185x over previous
//
#include <hip/hip_runtime.h>
#include <hip/hip_bf16.h>
#include <math.h>

typedef __attribute__((ext_vector_type(8))) __bf16 bf16x8;
typedef __attribute__((ext_vector_type(4))) __bf16 bf16x4;
typedef __attribute__((ext_vector_type(4))) float f32x4;
typedef __attribute__((ext_vector_type(4))) short short4_t;

#define D_MODEL 1024
#define SEQ     2048
#define BATCH   4
#define NH      16
#define HD      64
#define MROWS   (BATCH * SEQ)   // 8192

// 0.125 (1/sqrt(64)) * log2(e): folded into Q at the QKV-GEMM epilogue
#define SCALE_LOG2E 0.18033688011112042f

__device__ __forceinline__ void gld_lds16(const __bf16* g, __bf16* l) {
  __builtin_amdgcn_global_load_lds(
      (const __attribute__((address_space(1))) void*)g,
      (__attribute__((address_space(3))) void*)l, 16, 0, 0);
}

// ---------------- convert x: fp32 -> bf16, vectorized ----------------
__global__ __launch_bounds__(256) void cvt_x(const float* __restrict__ in,
                                             __bf16* __restrict__ out) {
  int i = (blockIdx.x * 256 + threadIdx.x) * 4;
  float4 f = *(const float4*)(in + i);
  bf16x4 o;
  o.x = (__bf16)f.x; o.y = (__bf16)f.y; o.z = (__bf16)f.z; o.w = (__bf16)f.w;
  *(bf16x4*)(out + i) = o;
}

// -- convert + transpose weights: fp32 [K][N] -> bf16 [N][K], all 4 in one
// dispatch (blockIdx.z selects the weight; saves 3 launch overheads) --
__global__ __launch_bounds__(256) void cvt_wt4(const float* __restrict__ W0,
                                               const float* __restrict__ W1,
                                               const float* __restrict__ W2,
                                               const float* __restrict__ W3,
                                               __bf16* __restrict__ Wqkv,
                                               __bf16* __restrict__ Wot) {
  __shared__ __bf16 t[32][33];
  int tx = threadIdx.x, ty = threadIdx.y;   // block (32,8)
  int z = blockIdx.z;
  const float* W = (z == 0) ? W0 : (z == 1) ? W1 : (z == 2) ? W2 : W3;
  __bf16* Wt = (z < 3) ? (Wqkv + (size_t)z * 1024 * 1024) : Wot;
  int n0 = blockIdx.x * 32, k0 = blockIdx.y * 32;
#pragma unroll
  for (int j = 0; j < 32; j += 8)
    t[ty + j][tx] = (__bf16)W[(size_t)(k0 + ty + j) * D_MODEL + n0 + tx];
  __syncthreads();
#pragma unroll
  for (int j = 0; j < 32; j += 8)
    Wt[(size_t)(n0 + ty + j) * D_MODEL + k0 + tx] = t[tx][ty + j];
}

// ---------------- GEMM: C[M,N] = A[M,K] @ Bt[N,K]^T  (bf16, m97 structure)
// R0 inner structure EXACTLY (R1-R3 falsified all pipelining variants).
// R11: + T1 XCD-chunked work swizzle. HW dispatch round-robins linear block
// id across the 8 XCDs (xcd = id%8); x-major ids mean the 8-16 blocks
// sharing one A-row panel were spread over ALL XCDs -> each XCD re-fetches
// the panel (up to 8x A traffic). Chunked remap wk=(id%8)*cpx + id/8 gives
// each XCD a CONTIGUOUS work range: A panels fetched once per chip, B
// (<=4 MB) L2-resident per XCD. Bijective: all grids are %8==0.
// Operand-swap trick: passing (Bfrag, Afrag) to MFMA yields C^T tiles, so a
// lane holds 4 CONSECUTIVE minor-dim outputs -> vector stores. Orientation
// per output layout:
// EPI 0 (SWAP): QK, N=2048. lane: token=l16, d=quad*4+i -> bf16x4 to [b,h,n,d]
//               (which = Q or K per 1024-col block; Q pre-scaled)
// EPI 1 (no swap): V, N=1024. lane: d=l16, token=quad*4+i -> bf16x4 to [b,h,d,n]
// EPI 2 (SWAP): proj, N=1024 fp32. lane: row=l16, col=quad*4+i -> float4+bias
template <int EPI>
__global__ __launch_bounds__(256) void gemm_bt(const __bf16* __restrict__ A,
                                               const __bf16* __restrict__ Bt,
                                               const float* __restrict__ bias,
                                               void* __restrict__ Cout) {
  constexpr int Kd = 1024;
  constexpr bool SWAP = (EPI != 1);
  constexpr int GX = (EPI == 0) ? 16 : 8;   // gridDim.x, compile-time
  __shared__ __bf16 As[128 * 32];
  __shared__ __bf16 Bs[128 * 32];
  const int tid = threadIdx.x;
  const int lane = tid & 63;
  const int w = tid >> 6;
  const int quad = lane >> 4, l16 = lane & 15;
  const int wr = w >> 1, wc = w & 1;

  // T1 XCD-chunked swizzle (bijective: nwg % 8 == 0 for all launches)
  const int id  = blockIdx.y * GX + blockIdx.x;
  const int nwg = GX * gridDim.y;
  const int wk  = (id & 7) * (nwg >> 3) + (id >> 3);
  const int tm = (wk / GX) * 128, tn = (wk % GX) * 128;

  f32x4 acc[4][4] = {};

  const int u0 = (w * 2) * 64 + lane;
  const int u1 = u0 + 64;
  const int rA0 = u0 >> 2, kofs0 = (u0 & 3) * 8;
  const int rA1 = u1 >> 2, kofs1 = (u1 & 3) * 8;
  const __bf16* gA0 = A + (size_t)(tm + rA0) * Kd + kofs0;
  const __bf16* gA1 = A + (size_t)(tm + rA1) * Kd + kofs1;
  const __bf16* gB0 = Bt + (size_t)(tn + rA0) * Kd + kofs0;
  const __bf16* gB1 = Bt + (size_t)(tn + rA1) * Kd + kofs1;
  __bf16* lA0 = As + (w * 2 + 0) * 512;
  __bf16* lA1 = As + (w * 2 + 1) * 512;
  __bf16* lB0 = Bs + (w * 2 + 0) * 512;
  __bf16* lB1 = Bs + (w * 2 + 1) * 512;

  for (int k0 = 0; k0 < Kd; k0 += 32) {
    gld_lds16(gA0 + k0, lA0);
    gld_lds16(gA1 + k0, lA1);
    gld_lds16(gB0 + k0, lB0);
    gld_lds16(gB1 + k0, lB1);
    __syncthreads();
    bf16x8 af[4], bfr[4];
#pragma unroll
    for (int t = 0; t < 4; ++t) {
      af[t]  = *(const bf16x8*)&As[(wr * 64 + t * 16 + l16) * 32 + quad * 8];
      bfr[t] = *(const bf16x8*)&Bs[(wc * 64 + t * 16 + l16) * 32 + quad * 8];
    }
#pragma unroll
    for (int mt = 0; mt < 4; ++mt)
#pragma unroll
      for (int nt = 0; nt < 4; ++nt) {
        if constexpr (SWAP)
          acc[mt][nt] = __builtin_amdgcn_mfma_f32_16x16x32_bf16(
              bfr[nt], af[mt], acc[mt][nt], 0, 0, 0);
        else
          acc[mt][nt] = __builtin_amdgcn_mfma_f32_16x16x32_bf16(
              af[mt], bfr[nt], acc[mt][nt], 0, 0, 0);
      }
    __syncthreads();
  }

#pragma unroll
  for (int mt = 0; mt < 4; ++mt)
#pragma unroll
    for (int nt = 0; nt < 4; ++nt) {
      if constexpr (EPI == 2) {
        // C^T tile: row of D = out col, col of D = out row (token)
        int gm  = tm + wr * 64 + mt * 16 + l16;        // token
        int gn0 = tn + wc * 64 + nt * 16 + quad * 4;   // col base
        float4 bv = *(const float4*)&bias[gn0];
        float4 o;
        o.x = acc[mt][nt][0] + bv.x;
        o.y = acc[mt][nt][1] + bv.y;
        o.z = acc[mt][nt][2] + bv.z;
        o.w = acc[mt][nt][3] + bv.w;
        *(float4*)&((float*)Cout)[(size_t)gm * 1024 + gn0] = o;
      } else if constexpr (EPI == 0) {
        int gm = tm + wr * 64 + mt * 16 + l16;         // token
        int f0 = tn + wc * 64 + nt * 16 + quad * 4;    // 0..2047 (Q|K)
        int which = f0 >> 10, col = f0 & 1023;
        int b = gm >> 11, nn = gm & 2047, h = col >> 6, d = col & 63;
        float s = (which == 0) ? SCALE_LOG2E : 1.0f;
        bf16x4 o;
        o[0] = (__bf16)(acc[mt][nt][0] * s);
        o[1] = (__bf16)(acc[mt][nt][1] * s);
        o[2] = (__bf16)(acc[mt][nt][2] * s);
        o[3] = (__bf16)(acc[mt][nt][3] * s);
        __bf16* op = (__bf16*)Cout + (size_t)which * (BATCH * SEQ * (size_t)D_MODEL) +
                     ((size_t)(b * NH + h) * SEQ + nn) * HD + d;
        *(bf16x4*)op = o;
      } else {   // EPI 1: V transposed, natural orientation
        int gm0 = tm + wr * 64 + mt * 16 + quad * 4;   // token base
        int gn  = tn + wc * 64 + nt * 16 + l16;        // feature 0..1023
        int b = gm0 >> 11, nn0 = gm0 & 2047, h = gn >> 6, d = gn & 63;
        bf16x4 o;
        o[0] = (__bf16)acc[mt][nt][0];
        o[1] = (__bf16)acc[mt][nt][1];
        o[2] = (__bf16)acc[mt][nt][2];
        o[3] = (__bf16)acc[mt][nt][3];
        __bf16* op = (__bf16*)Cout + ((size_t)(b * NH + h) * HD + d) * SEQ + nn0;
        *(bf16x4*)op = o;
      }
    }
}

// ---------------- causal flash attention, register-PV, double-buffered ----
// Grid (64, 16), block 256 (4 waves), one 128-row q-tile per block (R10
// base: VGPR 76, no spill). R10 showed occupancy is NOT the lever (21% vs
// 18.5%, dur flat) -- attn is VALU-critical-path bound (VALUBusy 47 vs
// MfmaUtil 30; ~450 VALU cyc vs ~115 MFMA cyc per iter).
// R11 cuts VALU work:
//  (a) row-sum via ones-column MFMA: sumacc[qq] += P-tile x ones computes
//      sum_k P[q,k] on the MATRIX pipe in exactly the accumulator row
//      layout rinv needs (q = quad*4+i) -- deletes 32 VALU adds/iter AND
//      the epilogue shuffle chain. Denominator now sums the same bf16 P
//      as the numerator (self-consistent).
//  (b) St zero-init hoisted through a loop-invariant zero C-operand --
//      deletes 32 v_mov/iter.
// XCD map: linear id = bx + 64*by, 64%8==0 -> xcd = bh%8: all 16 tiles of a
// bh share one XCD's L2 (R5's verified 4.5x FETCH win). Tile order
// interleaves heavy/light (by odd -> 15-by/2) for dispatch balance.
// S^T = mfma_16x16x32(Kfrag, Qfrag): lane holds S[q=l16][k=quad*4+i] -- this
// is EXACTLY the A-operand layout of mfma_f32_16x16x16_bf16 (k=quad*4+j), so
// PV runs straight from registers: no P LDS round-trip at all.
// V staged with XOR swizzle (unit = d*8 + ((k>>3)^(d&7))) so the b64 B-frag
// reads are bank-conflict-free. K/V double-buffered: 1 barrier/iter,
// prefetch of iter+1 overlaps compute of iter.
// (R1's K-swizzle REVERTED: cut bank conflicts 4.8M->3.2M but cost ~8%.)
__global__ __launch_bounds__(256, 2) void attn(const __bf16* __restrict__ Q,
                                               const __bf16* __restrict__ K,
                                               const __bf16* __restrict__ Vt,
                                               __bf16* __restrict__ ctx) {
  const int tid = threadIdx.x;
  const int lane = tid & 63, w = tid >> 6;
  const int quad = lane >> 4, l16 = lane & 15;
  const int byy = blockIdx.y;                       // 0..15
  const int tile = (byy & 1) ? (15 - (byy >> 1)) : (byy >> 1);
  const int bh = blockIdx.x;                        // 0..63
  const __bf16* qb = Q + (size_t)bh * SEQ * HD;
  const __bf16* kb = K + (size_t)bh * SEQ * HD;
  const __bf16* vb = Vt + (size_t)bh * HD * SEQ;

  __shared__ __bf16 KsAll[2 * 4096];   // [buf][half*2048 + key*32 + d]
  __shared__ __bf16 VsAll[2 * 4096];   // [buf][d*64 + ((k>>3)^(d&7))*8 + (k&7)]

  const int qmin = tile * 128 + w * 32;

  // Q fragments (B-operand, scale pre-folded)
  bf16x8 aq[2][2];
#pragma unroll
  for (int qq = 0; qq < 2; ++qq)
#pragma unroll
    for (int kk = 0; kk < 2; ++kk)
      aq[qq][kk] = *(const bf16x8*)(qb + (size_t)(qmin + qq * 16 + l16) * HD +
                                    kk * 32 + quad * 8);

  f32x4 acc[2][4] = {};    // [qq][cd] rows q=quad*4+i, cols d=cd*16+l16
  f32x4 sumacc[2] = {};    // [qq] denominator: rows q=quad*4+i (ones-MFMA)
  const f32x4 fz = {};     // loop-invariant zero C-operand for St init
  const short bf16_one = (short)0x3F80;
  const short4_t vones = {bf16_one, bf16_one, bf16_one, bf16_one};

  // staging decode. K: unit u -> key r=(u>>2)&63, half h=u>>8, elem e=(u&3)*8.
  // V (swizzled): unit u -> d=u>>3, kc=(u&7)^(d&7).
  const int u0 = w * 128 + lane;
  const int u1 = u0 + 64;
  const int kOffG0 = ((u0 >> 2) & 63) * HD + (u0 >> 8) * 32 + (u0 & 3) * 8;
  const int kOffG1 = ((u1 >> 2) & 63) * HD + (u1 >> 8) * 32 + (u1 & 3) * 8;
  const int vd0 = u0 >> 3, vd1 = u1 >> 3;
  const int vOffG0 = vd0 * SEQ + (((u0 & 7) ^ (vd0 & 7)) * 8);
  const int vOffG1 = vd1 * SEQ + (((u1 & 7) ^ (vd1 & 7)) * 8);

  auto stage = [&](int k0s, int bufsel) {
    __bf16* Kb = KsAll + bufsel * 4096;
    __bf16* Vb = VsAll + bufsel * 4096;
    gld_lds16(kb + (size_t)k0s * HD + kOffG0, Kb + u0 * 8);
    gld_lds16(kb + (size_t)k0s * HD + kOffG1, Kb + u1 * 8);
    gld_lds16(vb + k0s + vOffG0, Vb + u0 * 8);
    gld_lds16(vb + k0s + vOffG1, Vb + u1 * 8);
  };

  const int nIter = 2 * tile + 2;
  stage(0, 0);

  for (int it = 0; it < nIter; ++it) {
    __syncthreads();   // buf[it&1] staged; all waves done with buf[(it+1)&1]
    if (it + 1 < nIter) stage((it + 1) * 64, (it + 1) & 1);

    const int k0 = it * 64;
    if (k0 <= qmin + 31) {   // this wave still has unmasked keys here
      const __bf16* Kb = KsAll + (it & 1) * 4096;
      const __bf16* Vb = VsAll + (it & 1) * 4096;

      bf16x8 bk[4][2];          // A-operand K frags: rows = keys
#pragma unroll
      for (int kt = 0; kt < 4; ++kt)
#pragma unroll
        for (int kk = 0; kk < 2; ++kk)
          bk[kt][kk] = *(const bf16x8*)&Kb[kk * 2048 + (kt * 16 + l16) * 32 + quad * 8];

      // V B-frags for K=16 PV: vf[kt][cd] = V[k=kt*16+quad*4 ..+3][d=cd*16+l16]
      short4_t vf[4][4];
#pragma unroll
      for (int kt = 0; kt < 4; ++kt)
#pragma unroll
        for (int cd = 0; cd < 4; ++cd)
          vf[kt][cd] = *(const short4_t*)&Vb[(cd * 16 + l16) * 64 +
                                             (((kt * 2 + (quad >> 1)) ^ (l16 & 7)) * 8) +
                                             (quad & 1) * 4];

      // S^T[k][q]: rows k = k0+kt*16+quad*4+i, cols q = qmin+qq*16+l16
      f32x4 St[4][2];
#pragma unroll
      for (int kt = 0; kt < 4; ++kt)
#pragma unroll
        for (int qq = 0; qq < 2; ++qq) {
          St[kt][qq] = __builtin_amdgcn_mfma_f32_16x16x32_bf16(
              bk[kt][0], aq[qq][0], fz, 0, 0, 0);
          St[kt][qq] = __builtin_amdgcn_mfma_f32_16x16x32_bf16(
              bk[kt][1], aq[qq][1], St[kt][qq], 0, 0, 0);
        }
      const bool full = (k0 + 63 <= qmin);
#pragma unroll
      for (int kt = 0; kt < 4; ++kt)
#pragma unroll
        for (int qq = 0; qq < 2; ++qq) {
          float e0 = __builtin_amdgcn_exp2f(St[kt][qq][0]);
          float e1 = __builtin_amdgcn_exp2f(St[kt][qq][1]);
          float e2 = __builtin_amdgcn_exp2f(St[kt][qq][2]);
          float e3 = __builtin_amdgcn_exp2f(St[kt][qq][3]);
          if (!full) {
            int kg = k0 + kt * 16 + quad * 4;
            int qg = qmin + qq * 16 + l16;
            if (kg + 0 > qg) e0 = 0.f;
            if (kg + 1 > qg) e1 = 0.f;
            if (kg + 2 > qg) e2 = 0.f;
            if (kg + 3 > qg) e3 = 0.f;
          }
          short4_t ap;
          ap[0] = __builtin_bit_cast(short, (__bf16)e0);
          ap[1] = __builtin_bit_cast(short, (__bf16)e1);
          ap[2] = __builtin_bit_cast(short, (__bf16)e2);
          ap[3] = __builtin_bit_cast(short, (__bf16)e3);
          // denominator on the matrix pipe: sum_k P[q,k] (rows q=quad*4+i)
          sumacc[qq] = __builtin_amdgcn_mfma_f32_16x16x16bf16_1k(
              ap, vones, sumacc[qq], 0, 0, 0);
          // PV straight from registers: O[q][d] tiles over d
#pragma unroll
          for (int cd = 0; cd < 4; ++cd)
            acc[qq][cd] = __builtin_amdgcn_mfma_f32_16x16x16bf16_1k(
                ap, vf[kt][cd], acc[qq][cd], 0, 0, 0);
        }
    }
  }

  const int bb = bh >> 4, hh = bh & 15;
#pragma unroll
  for (int qq = 0; qq < 2; ++qq) {
    // sumacc[qq][i] = full row sum for q = qmin+qq*16+quad*4+i (all l16 equal)
    float rinv[4];
#pragma unroll
    for (int i = 0; i < 4; ++i)
      rinv[i] = 1.0f / sumacc[qq][i];
#pragma unroll
    for (int c = 0; c < 4; ++c)
#pragma unroll
      for (int i = 0; i < 4; ++i) {
        int q = qmin + qq * 16 + quad * 4 + i;
        float o = acc[qq][c][i] * rinv[i];
        ctx[((size_t)(bb * SEQ + q)) * D_MODEL + hh * HD + c * 16 + l16] = (__bf16)o;
      }
  }
}

extern "C" void kernel_launch(void* const* d_in, const int* in_sizes, int n_in,
                              void* d_out, int out_size, void* d_ws, size_t ws_size,
                              hipStream_t stream) {
  const float* x  = (const float*)d_in[0];
  const float* Wq = (const float*)d_in[1];
  const float* Wk = (const float*)d_in[2];
  const float* Wv = (const float*)d_in[3];
  const float* Wo = (const float*)d_in[4];
  const float* bo = (const float*)d_in[5];
  float* out = (float*)d_out;
  char* ws = (char*)d_ws;
  const size_t MB = 1024 * 1024;
  __bf16* xb   = (__bf16*)(ws);             // 16 MB; reused as ctx after attn
  __bf16* Wqkv = (__bf16*)(ws + 16 * MB);   // 6 MB: Wqt|Wkt|Wvt contiguous
  __bf16* Wot  = (__bf16*)(ws + 22 * MB);   // 2 MB
  __bf16* Qh   = (__bf16*)(ws + 24 * MB);   // 16 MB [b,h,n,d], pre-scaled
  __bf16* Kh   = (__bf16*)(ws + 40 * MB);   // 16 MB [b,h,n,d]
  __bf16* Vth  = (__bf16*)(ws + 56 * MB);   // 16 MB [b,h,d,n]
  __bf16* ctx  = xb;                        // alias: xb dead after QKV GEMM

  cvt_x<<<MROWS * D_MODEL / (256 * 4), 256, 0, stream>>>(x, xb);
  cvt_wt4<<<dim3(32, 32, 4), dim3(32, 8), 0, stream>>>(Wq, Wk, Wv, Wo, Wqkv, Wot);

  // QK projection (swapped-operand epilogue), then V projection (natural)
  gemm_bt<0><<<dim3(16, 64), 256, 0, stream>>>(xb, Wqkv, nullptr, Qh);
  gemm_bt<1><<<dim3(8, 64), 256, 0, stream>>>(xb, Wqkv + 2 * 1024 * 1024, nullptr, Vth);

  attn<<<dim3(64, 16), 256, 0, stream>>>(Qh, Kh, Vth, ctx);

  gemm_bt<2><<<dim3(8, 64), 256, 0, stream>>>(ctx, Wot, bo, out);
}

// Round 16
// 255.715 us; speedup vs baseline: 1.2019x; 1.0212x over previous
//
#include <hip/hip_runtime.h>
#include <hip/hip_bf16.h>
#include <math.h>

typedef __attribute__((ext_vector_type(8))) __bf16 bf16x8;
typedef __attribute__((ext_vector_type(4))) __bf16 bf16x4;
typedef __attribute__((ext_vector_type(4))) float f32x4;
typedef __attribute__((ext_vector_type(4))) short short4_t;

#define D_MODEL 1024
#define SEQ     2048
#define BATCH   4
#define NH      16
#define HD      64
#define MROWS   (BATCH * SEQ)   // 8192

// 0.125 (1/sqrt(64)) * log2(e): folded into Q at the QKV-GEMM epilogue
#define SCALE_LOG2E 0.18033688011112042f

__device__ __forceinline__ void gld_lds16(const __bf16* g, __bf16* l) {
  __builtin_amdgcn_global_load_lds(
      (const __attribute__((address_space(1))) void*)g,
      (__attribute__((address_space(3))) void*)l, 16, 0, 0);
}

// ---------------- convert x: fp32 -> bf16, vectorized ----------------
__global__ __launch_bounds__(256) void cvt_x(const float* __restrict__ in,
                                             __bf16* __restrict__ out) {
  int i = (blockIdx.x * 256 + threadIdx.x) * 4;
  float4 f = *(const float4*)(in + i);
  bf16x4 o;
  o.x = (__bf16)f.x; o.y = (__bf16)f.y; o.z = (__bf16)f.z; o.w = (__bf16)f.w;
  *(bf16x4*)(out + i) = o;
}

// -- convert + transpose weights: fp32 [K][N] -> bf16 [N][K], all 4 in one
// dispatch (blockIdx.z selects the weight; saves 3 launch overheads) --
__global__ __launch_bounds__(256) void cvt_wt4(const float* __restrict__ W0,
                                               const float* __restrict__ W1,
                                               const float* __restrict__ W2,
                                               const float* __restrict__ W3,
                                               __bf16* __restrict__ Wqkv,
                                               __bf16* __restrict__ Wot) {
  __shared__ __bf16 t[32][33];
  int tx = threadIdx.x, ty = threadIdx.y;   // block (32,8)
  int z = blockIdx.z;
  const float* W = (z == 0) ? W0 : (z == 1) ? W1 : (z == 2) ? W2 : W3;
  __bf16* Wt = (z < 3) ? (Wqkv + (size_t)z * 1024 * 1024) : Wot;
  int n0 = blockIdx.x * 32, k0 = blockIdx.y * 32;
#pragma unroll
  for (int j = 0; j < 32; j += 8)
    t[ty + j][tx] = (__bf16)W[(size_t)(k0 + ty + j) * D_MODEL + n0 + tx];
  __syncthreads();
#pragma unroll
  for (int j = 0; j < 32; j += 8)
    Wt[(size_t)(n0 + ty + j) * D_MODEL + k0 + tx] = t[tx][ty + j];
}

// ---------------- GEMM: C[M,N] = A[M,K] @ Bt[N,K]^T  (bf16)
// R12: m97 2-barrier sync UNCHANGED (R1-R3 falsified all sync restructures)
// but BK=32 -> 64: 32 KB LDS single-buffer (occupancy stays VGPR-capped at
// ~3 blocks/CU, unlike m132's BK=128/64KB), 8 gld_lds + 32 MFMA between
// barriers = 2x amortization. LDS holds two K-major 32-col sub-tiles
// ([kk][row][32]) so fragment addressing / bank profile is byte-identical
// to the proven m97 pattern. Load:compute per K-element unchanged.
// + T1 XCD-chunked work swizzle (R11, ~5us): chunked remap gives each XCD
// a contiguous work range -> A panels fetched once per chip, B L2-resident.
// Operand-swap trick: passing (Bfrag, Afrag) to MFMA yields C^T tiles, so a
// lane holds 4 CONSECUTIVE minor-dim outputs -> vector stores. Orientation
// per output layout:
// EPI 0 (SWAP): QK, N=2048. lane: token=l16, d=quad*4+i -> bf16x4 to [b,h,n,d]
//               (which = Q or K per 1024-col block; Q pre-scaled)
// EPI 1 (no swap): V, N=1024. lane: d=l16, token=quad*4+i -> bf16x4 to [b,h,d,n]
// EPI 2 (SWAP): proj, N=1024 fp32. lane: row=l16, col=quad*4+i -> float4+bias
template <int EPI>
__global__ __launch_bounds__(256) void gemm_bt(const __bf16* __restrict__ A,
                                               const __bf16* __restrict__ Bt,
                                               const float* __restrict__ bias,
                                               void* __restrict__ Cout) {
  constexpr int Kd = 1024;
  constexpr bool SWAP = (EPI != 1);
  constexpr int GX = (EPI == 0) ? 16 : 8;   // gridDim.x, compile-time
  __shared__ __bf16 As[128 * 64];   // [kk][row][32]: kk*4096 + row*32 + c
  __shared__ __bf16 Bs[128 * 64];
  const int tid = threadIdx.x;
  const int lane = tid & 63;
  const int w = tid >> 6;
  const int quad = lane >> 4, l16 = lane & 15;
  const int wr = w >> 1, wc = w & 1;

  // T1 XCD-chunked swizzle (bijective: nwg % 8 == 0 for all launches)
  const int id  = blockIdx.y * GX + blockIdx.x;
  const int nwg = GX * gridDim.y;
  const int wk  = (id & 7) * (nwg >> 3) + (id >> 3);
  const int tm = (wk / GX) * 128, tn = (wk % GX) * 128;

  f32x4 acc[4][4] = {};

  // staging: 1024 16B-units per matrix; unit s -> kk = s>>9,
  // row = (s>>2)&127, 16B chunk c = s&3 (covers cols kk*32 + c*8 .. +7).
  // LDS dest linear at s*8 elems (wave-uniform base + lane*16B); the
  // GLOBAL source is decoded so linear-dest == [kk][row][32] layout.
  const __bf16* gA[4]; const __bf16* gB[4]; int dst[4];
#pragma unroll
  for (int j = 0; j < 4; ++j) {
    int s = w * 256 + j * 64 + lane;
    int row = (s >> 2) & 127, kk = s >> 9, c = (s & 3) * 8;
    int go = kk * 32 + c;
    gA[j] = A + (size_t)(tm + row) * Kd + go;
    gB[j] = Bt + (size_t)(tn + row) * Kd + go;
    dst[j] = s * 8;
  }

  for (int k0 = 0; k0 < Kd; k0 += 64) {
#pragma unroll
    for (int j = 0; j < 4; ++j) {
      gld_lds16(gA[j] + k0, As + dst[j]);
      gld_lds16(gB[j] + k0, Bs + dst[j]);
    }
    __syncthreads();
#pragma unroll
    for (int kk = 0; kk < 2; ++kk) {
      bf16x8 af[4], bfr[4];
#pragma unroll
      for (int t = 0; t < 4; ++t) {
        af[t]  = *(const bf16x8*)&As[kk * 4096 + (wr * 64 + t * 16 + l16) * 32 + quad * 8];
        bfr[t] = *(const bf16x8*)&Bs[kk * 4096 + (wc * 64 + t * 16 + l16) * 32 + quad * 8];
      }
#pragma unroll
      for (int mt = 0; mt < 4; ++mt)
#pragma unroll
        for (int nt = 0; nt < 4; ++nt) {
          if constexpr (SWAP)
            acc[mt][nt] = __builtin_amdgcn_mfma_f32_16x16x32_bf16(
                bfr[nt], af[mt], acc[mt][nt], 0, 0, 0);
          else
            acc[mt][nt] = __builtin_amdgcn_mfma_f32_16x16x32_bf16(
                af[mt], bfr[nt], acc[mt][nt], 0, 0, 0);
        }
    }
    __syncthreads();
  }

#pragma unroll
  for (int mt = 0; mt < 4; ++mt)
#pragma unroll
    for (int nt = 0; nt < 4; ++nt) {
      if constexpr (EPI == 2) {
        // C^T tile: row of D = out col, col of D = out row (token)
        int gm  = tm + wr * 64 + mt * 16 + l16;        // token
        int gn0 = tn + wc * 64 + nt * 16 + quad * 4;   // col base
        float4 bv = *(const float4*)&bias[gn0];
        float4 o;
        o.x = acc[mt][nt][0] + bv.x;
        o.y = acc[mt][nt][1] + bv.y;
        o.z = acc[mt][nt][2] + bv.z;
        o.w = acc[mt][nt][3] + bv.w;
        *(float4*)&((float*)Cout)[(size_t)gm * 1024 + gn0] = o;
      } else if constexpr (EPI == 0) {
        int gm = tm + wr * 64 + mt * 16 + l16;         // token
        int f0 = tn + wc * 64 + nt * 16 + quad * 4;    // 0..2047 (Q|K)
        int which = f0 >> 10, col = f0 & 1023;
        int b = gm >> 11, nn = gm & 2047, h = col >> 6, d = col & 63;
        float s = (which == 0) ? SCALE_LOG2E : 1.0f;
        bf16x4 o;
        o[0] = (__bf16)(acc[mt][nt][0] * s);
        o[1] = (__bf16)(acc[mt][nt][1] * s);
        o[2] = (__bf16)(acc[mt][nt][2] * s);
        o[3] = (__bf16)(acc[mt][nt][3] * s);
        __bf16* op = (__bf16*)Cout + (size_t)which * (BATCH * SEQ * (size_t)D_MODEL) +
                     ((size_t)(b * NH + h) * SEQ + nn) * HD + d;
        *(bf16x4*)op = o;
      } else {   // EPI 1: V transposed, natural orientation
        int gm0 = tm + wr * 64 + mt * 16 + quad * 4;   // token base
        int gn  = tn + wc * 64 + nt * 16 + l16;        // feature 0..1023
        int b = gm0 >> 11, nn0 = gm0 & 2047, h = gn >> 6, d = gn & 63;
        bf16x4 o;
        o[0] = (__bf16)acc[mt][nt][0];
        o[1] = (__bf16)acc[mt][nt][1];
        o[2] = (__bf16)acc[mt][nt][2];
        o[3] = (__bf16)acc[mt][nt][3];
        __bf16* op = (__bf16*)Cout + ((size_t)(b * NH + h) * HD + d) * SEQ + nn0;
        *(bf16x4*)op = o;
      }
    }
}

// ---------------- causal flash attention, register-PV, double-buffered ----
// R11 version kept verbatim (best known: ~69.5 us; VGPR 80, no spill).
// Session conclusion: attn is issue-slot saturated (MfmaUtil 34 + VALU 43;
// dur pinned 68-70 across occupancy 18->26% and VALU cuts) -- further gains
// need a full 8-warp 32x32 rewrite, not increments.
// Grid (64, 16), one 128-row q-tile per block; xcd = bh%8 so all 16 tiles
// of a bh share one XCD's L2 (R5's verified 4.5x FETCH win); heavy/light
// tile interleave over blockIdx.y.
// Row-sum on the MATRIX pipe via ones-column MFMA (R11); St zero-init via
// loop-invariant zero C-operand.
// S^T = mfma_16x16x32(Kfrag, Qfrag): lane holds S[q=l16][k=quad*4+i] == the
// A-operand layout of mfma_f32_16x16x16_bf16 -> PV straight from registers.
// V staged with XOR swizzle; K/V double-buffered: 1 barrier/iter.
__global__ __launch_bounds__(256, 2) void attn(const __bf16* __restrict__ Q,
                                               const __bf16* __restrict__ K,
                                               const __bf16* __restrict__ Vt,
                                               __bf16* __restrict__ ctx) {
  const int tid = threadIdx.x;
  const int lane = tid & 63, w = tid >> 6;
  const int quad = lane >> 4, l16 = lane & 15;
  const int byy = blockIdx.y;                       // 0..15
  const int tile = (byy & 1) ? (15 - (byy >> 1)) : (byy >> 1);
  const int bh = blockIdx.x;                        // 0..63
  const __bf16* qb = Q + (size_t)bh * SEQ * HD;
  const __bf16* kb = K + (size_t)bh * SEQ * HD;
  const __bf16* vb = Vt + (size_t)bh * HD * SEQ;

  __shared__ __bf16 KsAll[2 * 4096];   // [buf][half*2048 + key*32 + d]
  __shared__ __bf16 VsAll[2 * 4096];   // [buf][d*64 + ((k>>3)^(d&7))*8 + (k&7)]

  const int qmin = tile * 128 + w * 32;

  // Q fragments (B-operand, scale pre-folded)
  bf16x8 aq[2][2];
#pragma unroll
  for (int qq = 0; qq < 2; ++qq)
#pragma unroll
    for (int kk = 0; kk < 2; ++kk)
      aq[qq][kk] = *(const bf16x8*)(qb + (size_t)(qmin + qq * 16 + l16) * HD +
                                    kk * 32 + quad * 8);

  f32x4 acc[2][4] = {};    // [qq][cd] rows q=quad*4+i, cols d=cd*16+l16
  f32x4 sumacc[2] = {};    // [qq] denominator: rows q=quad*4+i (ones-MFMA)
  const f32x4 fz = {};     // loop-invariant zero C-operand for St init
  const short bf16_one = (short)0x3F80;
  const short4_t vones = {bf16_one, bf16_one, bf16_one, bf16_one};

  // staging decode. K: unit u -> key r=(u>>2)&63, half h=u>>8, elem e=(u&3)*8.
  // V (swizzled): unit u -> d=u>>3, kc=(u&7)^(d&7).
  const int u0 = w * 128 + lane;
  const int u1 = u0 + 64;
  const int kOffG0 = ((u0 >> 2) & 63) * HD + (u0 >> 8) * 32 + (u0 & 3) * 8;
  const int kOffG1 = ((u1 >> 2) & 63) * HD + (u1 >> 8) * 32 + (u1 & 3) * 8;
  const int vd0 = u0 >> 3, vd1 = u1 >> 3;
  const int vOffG0 = vd0 * SEQ + (((u0 & 7) ^ (vd0 & 7)) * 8);
  const int vOffG1 = vd1 * SEQ + (((u1 & 7) ^ (vd1 & 7)) * 8);

  auto stage = [&](int k0s, int bufsel) {
    __bf16* Kb = KsAll + bufsel * 4096;
    __bf16* Vb = VsAll + bufsel * 4096;
    gld_lds16(kb + (size_t)k0s * HD + kOffG0, Kb + u0 * 8);
    gld_lds16(kb + (size_t)k0s * HD + kOffG1, Kb + u1 * 8);
    gld_lds16(vb + k0s + vOffG0, Vb + u0 * 8);
    gld_lds16(vb + k0s + vOffG1, Vb + u1 * 8);
  };

  const int nIter = 2 * tile + 2;
  stage(0, 0);

  for (int it = 0; it < nIter; ++it) {
    __syncthreads();   // buf[it&1] staged; all waves done with buf[(it+1)&1]
    if (it + 1 < nIter) stage((it + 1) * 64, (it + 1) & 1);

    const int k0 = it * 64;
    if (k0 <= qmin + 31) {   // this wave still has unmasked keys here
      const __bf16* Kb = KsAll + (it & 1) * 4096;
      const __bf16* Vb = VsAll + (it & 1) * 4096;

      bf16x8 bk[4][2];          // A-operand K frags: rows = keys
#pragma unroll
      for (int kt = 0; kt < 4; ++kt)
#pragma unroll
        for (int kk = 0; kk < 2; ++kk)
          bk[kt][kk] = *(const bf16x8*)&Kb[kk * 2048 + (kt * 16 + l16) * 32 + quad * 8];

      // V B-frags for K=16 PV: vf[kt][cd] = V[k=kt*16+quad*4 ..+3][d=cd*16+l16]
      short4_t vf[4][4];
#pragma unroll
      for (int kt = 0; kt < 4; ++kt)
#pragma unroll
        for (int cd = 0; cd < 4; ++cd)
          vf[kt][cd] = *(const short4_t*)&Vb[(cd * 16 + l16) * 64 +
                                             (((kt * 2 + (quad >> 1)) ^ (l16 & 7)) * 8) +
                                             (quad & 1) * 4];

      // S^T[k][q]: rows k = k0+kt*16+quad*4+i, cols q = qmin+qq*16+l16
      f32x4 St[4][2];
#pragma unroll
      for (int kt = 0; kt < 4; ++kt)
#pragma unroll
        for (int qq = 0; qq < 2; ++qq) {
          St[kt][qq] = __builtin_amdgcn_mfma_f32_16x16x32_bf16(
              bk[kt][0], aq[qq][0], fz, 0, 0, 0);
          St[kt][qq] = __builtin_amdgcn_mfma_f32_16x16x32_bf16(
              bk[kt][1], aq[qq][1], St[kt][qq], 0, 0, 0);
        }
      const bool full = (k0 + 63 <= qmin);
#pragma unroll
      for (int kt = 0; kt < 4; ++kt)
#pragma unroll
        for (int qq = 0; qq < 2; ++qq) {
          float e0 = __builtin_amdgcn_exp2f(St[kt][qq][0]);
          float e1 = __builtin_amdgcn_exp2f(St[kt][qq][1]);
          float e2 = __builtin_amdgcn_exp2f(St[kt][qq][2]);
          float e3 = __builtin_amdgcn_exp2f(St[kt][qq][3]);
          if (!full) {
            int kg = k0 + kt * 16 + quad * 4;
            int qg = qmin + qq * 16 + l16;
            if (kg + 0 > qg) e0 = 0.f;
            if (kg + 1 > qg) e1 = 0.f;
            if (kg + 2 > qg) e2 = 0.f;
            if (kg + 3 > qg) e3 = 0.f;
          }
          short4_t ap;
          ap[0] = __builtin_bit_cast(short, (__bf16)e0);
          ap[1] = __builtin_bit_cast(short, (__bf16)e1);
          ap[2] = __builtin_bit_cast(short, (__bf16)e2);
          ap[3] = __builtin_bit_cast(short, (__bf16)e3);
          // denominator on the matrix pipe: sum_k P[q,k] (rows q=quad*4+i)
          sumacc[qq] = __builtin_amdgcn_mfma_f32_16x16x16bf16_1k(
              ap, vones, sumacc[qq], 0, 0, 0);
          // PV straight from registers: O[q][d] tiles over d
#pragma unroll
          for (int cd = 0; cd < 4; ++cd)
            acc[qq][cd] = __builtin_amdgcn_mfma_f32_16x16x16bf16_1k(
                ap, vf[kt][cd], acc[qq][cd], 0, 0, 0);
        }
    }
  }

  const int bb = bh >> 4, hh = bh & 15;
#pragma unroll
  for (int qq = 0; qq < 2; ++qq) {
    // sumacc[qq][i] = full row sum for q = qmin+qq*16+quad*4+i (all l16 equal)
    float rinv[4];
#pragma unroll
    for (int i = 0; i < 4; ++i)
      rinv[i] = 1.0f / sumacc[qq][i];
#pragma unroll
    for (int c = 0; c < 4; ++c)
#pragma unroll
      for (int i = 0; i < 4; ++i) {
        int q = qmin + qq * 16 + quad * 4 + i;
        float o = acc[qq][c][i] * rinv[i];
        ctx[((size_t)(bb * SEQ + q)) * D_MODEL + hh * HD + c * 16 + l16] = (__bf16)o;
      }
  }
}

extern "C" void kernel_launch(void* const* d_in, const int* in_sizes, int n_in,
                              void* d_out, int out_size, void* d_ws, size_t ws_size,
                              hipStream_t stream) {
  const float* x  = (const float*)d_in[0];
  const float* Wq = (const float*)d_in[1];
  const float* Wk = (const float*)d_in[2];
  const float* Wv = (const float*)d_in[3];
  const float* Wo = (const float*)d_in[4];
  const float* bo = (const float*)d_in[5];
  float* out = (float*)d_out;
  char* ws = (char*)d_ws;
  const size_t MB = 1024 * 1024;
  __bf16* xb   = (__bf16*)(ws);             // 16 MB; reused as ctx after attn
  __bf16* Wqkv = (__bf16*)(ws + 16 * MB);   // 6 MB: Wqt|Wkt|Wvt contiguous
  __bf16* Wot  = (__bf16*)(ws + 22 * MB);   // 2 MB
  __bf16* Qh   = (__bf16*)(ws + 24 * MB);   // 16 MB [b,h,n,d], pre-scaled
  __bf16* Kh   = (__bf16*)(ws + 40 * MB);   // 16 MB [b,h,n,d]
  __bf16* Vth  = (__bf16*)(ws + 56 * MB);   // 16 MB [b,h,d,n]
  __bf16* ctx  = xb;                        // alias: xb dead after QKV GEMM

  cvt_x<<<MROWS * D_MODEL / (256 * 4), 256, 0, stream>>>(x, xb);
  cvt_wt4<<<dim3(32, 32, 4), dim3(32, 8), 0, stream>>>(Wq, Wk, Wv, Wo, Wqkv, Wot);

  // QK projection (swapped-operand epilogue), then V projection (natural)
  gemm_bt<0><<<dim3(16, 64), 256, 0, stream>>>(xb, Wqkv, nullptr, Qh);
  gemm_bt<1><<<dim3(8, 64), 256, 0, stream>>>(xb, Wqkv + 2 * 1024 * 1024, nullptr, Vth);

  attn<<<dim3(64, 16), 256, 0, stream>>>(Qh, Kh, Vth, ctx);

  gemm_bt<2><<<dim3(8, 64), 256, 0, stream>>>(ctx, Wot, bo, out);
}

// Round 17
// 252.148 us; speedup vs baseline: 1.2189x; 1.0141x over previous
//
#include <hip/hip_runtime.h>
#include <hip/hip_bf16.h>
#include <math.h>

typedef __attribute__((ext_vector_type(8))) __bf16 bf16x8;
typedef __attribute__((ext_vector_type(4))) __bf16 bf16x4;
typedef __attribute__((ext_vector_type(4))) float f32x4;
typedef __attribute__((ext_vector_type(4))) short short4_t;

#define D_MODEL 1024
#define SEQ     2048
#define BATCH   4
#define NH      16
#define HD      64
#define MROWS   (BATCH * SEQ)   // 8192

// 0.125 (1/sqrt(64)) * log2(e): folded into Q at the QKV-GEMM epilogue
#define SCALE_LOG2E 0.18033688011112042f

__device__ __forceinline__ void gld_lds16(const __bf16* g, __bf16* l) {
  __builtin_amdgcn_global_load_lds(
      (const __attribute__((address_space(1))) void*)g,
      (__attribute__((address_space(3))) void*)l, 16, 0, 0);
}

// ---------------- convert x: fp32 -> bf16, vectorized ----------------
__global__ __launch_bounds__(256) void cvt_x(const float* __restrict__ in,
                                             __bf16* __restrict__ out) {
  int i = (blockIdx.x * 256 + threadIdx.x) * 4;
  float4 f = *(const float4*)(in + i);
  bf16x4 o;
  o.x = (__bf16)f.x; o.y = (__bf16)f.y; o.z = (__bf16)f.z; o.w = (__bf16)f.w;
  *(bf16x4*)(out + i) = o;
}

// -- convert + transpose weights: fp32 [K][N] -> bf16 [N][K], all 4 in one
// dispatch (blockIdx.z selects the weight; saves 3 launch overheads) --
__global__ __launch_bounds__(256) void cvt_wt4(const float* __restrict__ W0,
                                               const float* __restrict__ W1,
                                               const float* __restrict__ W2,
                                               const float* __restrict__ W3,
                                               __bf16* __restrict__ Wqkv,
                                               __bf16* __restrict__ Wot) {
  __shared__ __bf16 t[32][33];
  int tx = threadIdx.x, ty = threadIdx.y;   // block (32,8)
  int z = blockIdx.z;
  const float* W = (z == 0) ? W0 : (z == 1) ? W1 : (z == 2) ? W2 : W3;
  __bf16* Wt = (z < 3) ? (Wqkv + (size_t)z * 1024 * 1024) : Wot;
  int n0 = blockIdx.x * 32, k0 = blockIdx.y * 32;
#pragma unroll
  for (int j = 0; j < 32; j += 8)
    t[ty + j][tx] = (__bf16)W[(size_t)(k0 + ty + j) * D_MODEL + n0 + tx];
  __syncthreads();
#pragma unroll
  for (int j = 0; j < 32; j += 8)
    Wt[(size_t)(n0 + ty + j) * D_MODEL + k0 + tx] = t[tx][ty + j];
}

// ------- gemm256: QK projection, 256x256 tile, 2-phase dbuf (R17) -------
// C[8192, 2048] = xb @ [Wqt|Wkt]^T, epilogue = EPI0 (split Q/K, Q scaled).
// Anchor: m230-V0/m248v2 = 666-682 TF refcheck'd at 256^2 tile, K=1024,
// simple 2-phase -- vs our 128^2 family's ~450-500 TF. The decisive delta
// vs R3's FAILED 256x128 attempt: 64 MFMA/barrier/wave (not 32) and 131
// FLOP per staged byte (not 87). Sync pattern is R1's verified-safe one:
// stage(t+1 -> buf^1) BEFORE compute(buf), ONE __syncthreads per K-tile
// (implicit vmcnt(0)+lgkmcnt(0) drains the prefetch that had the whole
// 64-MFMA phase to fly; fences reads of buf before overwrite).
// 512 threads / 8 waves (2M x 4N; per-wave 128x64 out = acc[8][4]).
// LDS 2 x 64 KB = 128 KB -> 1 block/CU; grid (8,32) = 256 blocks = 1/CU.
// LDS layout per buffer: [kk][row][32] sub-tiles (m97 bank profile);
// linear gld_lds dest == that layout via global-source decode (rule 21).
__global__ __launch_bounds__(512) void gemm256(const __bf16* __restrict__ A,
                                               const __bf16* __restrict__ Bt,
                                               __bf16* __restrict__ Cout) {
  constexpr int Kd = 1024;
  constexpr int NT = Kd / 64;          // 16 K-tiles
  __shared__ __bf16 As[2][256 * 64];   // [buf][kk*8192 + row*32 + c8*8]
  __shared__ __bf16 Bs[2][256 * 64];
  const int tid = threadIdx.x;
  const int lane = tid & 63;
  const int w = tid >> 6;              // 0..7
  const int quad = lane >> 4, l16 = lane & 15;
  const int wr = w >> 2, wc = w & 3;   // 2M x 4N wave grid

  // T1 XCD-chunked swizzle: grid (8,32), nwg=256, %8==0 -> bijective
  const int id  = blockIdx.y * 8 + blockIdx.x;
  const int wk  = (id & 7) * 32 + (id >> 3);
  const int tm = (wk >> 3) * 256, tn = (wk & 7) * 256;

  f32x4 acc[8][4] = {};

  // staging: 2048 16B-units per matrix (256 rows x 64 cols x 2B); unit s ->
  // kk = s>>10, row = (s>>2)&255, chunk c = (s&3)*8. 4 units/thread/matrix.
  const __bf16* gA[4]; const __bf16* gB[4]; int dst[4];
#pragma unroll
  for (int j = 0; j < 4; ++j) {
    int s = j * 512 + tid;
    int row = (s >> 2) & 255, kk = s >> 10, c = (s & 3) * 8;
    int go = kk * 32 + c;
    gA[j] = A + (size_t)(tm + row) * Kd + go;
    gB[j] = Bt + (size_t)(tn + row) * Kd + go;
    dst[j] = s * 8;
  }

  auto stage = [&](int k0s, int bf) {
#pragma unroll
    for (int j = 0; j < 4; ++j) {
      gld_lds16(gA[j] + k0s, &As[bf][dst[j]]);
      gld_lds16(gB[j] + k0s, &Bs[bf][dst[j]]);
    }
  };

  stage(0, 0);
  __syncthreads();

  int buf = 0;
  for (int t = 0; t < NT; ++t) {
    if (t + 1 < NT) stage((t + 1) * 64, buf ^ 1);
#pragma unroll
    for (int kk = 0; kk < 2; ++kk) {
      bf16x8 af[8], bfr[4];
#pragma unroll
      for (int x = 0; x < 8; ++x)
        af[x] = *(const bf16x8*)&As[buf][kk * 8192 + (wr * 128 + x * 16 + l16) * 32 + quad * 8];
#pragma unroll
      for (int y = 0; y < 4; ++y)
        bfr[y] = *(const bf16x8*)&Bs[buf][kk * 8192 + (wc * 64 + y * 16 + l16) * 32 + quad * 8];
#pragma unroll
      for (int mt = 0; mt < 8; ++mt)
#pragma unroll
        for (int nt = 0; nt < 4; ++nt)
          acc[mt][nt] = __builtin_amdgcn_mfma_f32_16x16x32_bf16(
              bfr[nt], af[mt], acc[mt][nt], 0, 0, 0);   // SWAP: C^T tiles
    }
    __syncthreads();
    buf ^= 1;
  }

  // EPI0 epilogue: lane holds token=l16, d-quad=quad*4+i (C^T layout)
#pragma unroll
  for (int mt = 0; mt < 8; ++mt)
#pragma unroll
    for (int nt = 0; nt < 4; ++nt) {
      int gm = tm + wr * 128 + mt * 16 + l16;        // token
      int f0 = tn + wc * 64 + nt * 16 + quad * 4;    // 0..2047 (Q|K)
      int which = f0 >> 10, col = f0 & 1023;
      int b = gm >> 11, nn = gm & 2047, h = col >> 6, d = col & 63;
      float s = (which == 0) ? SCALE_LOG2E : 1.0f;
      bf16x4 o;
      o[0] = (__bf16)(acc[mt][nt][0] * s);
      o[1] = (__bf16)(acc[mt][nt][1] * s);
      o[2] = (__bf16)(acc[mt][nt][2] * s);
      o[3] = (__bf16)(acc[mt][nt][3] * s);
      __bf16* op = Cout + (size_t)which * (BATCH * SEQ * (size_t)D_MODEL) +
                   ((size_t)(b * NH + h) * SEQ + nn) * HD + d;
      *(bf16x4*)op = o;
    }
}

// ---------------- GEMM: C[M,N] = A[M,K] @ Bt[N,K]^T  (bf16)
// R16-verified config for gemm1/2 (N=1024: a 256^2 grid would idle half the
// chip, so these keep 128^2): m97 2-barrier sync, BK=64 ([kk][row][32]
// sub-tiles, 32 KB LDS), T1 XCD-chunk. Pool win vs BK=32: ~5 us.
// Operand-swap trick as before. EPI 1 (no swap): V -> [b,h,d,n].
// EPI 2 (SWAP): out proj, fp32 + bias.
template <int EPI>
__global__ __launch_bounds__(256) void gemm_bt(const __bf16* __restrict__ A,
                                               const __bf16* __restrict__ Bt,
                                               const float* __restrict__ bias,
                                               void* __restrict__ Cout) {
  constexpr int Kd = 1024;
  constexpr bool SWAP = (EPI != 1);
  constexpr int GX = 8;   // gridDim.x (both remaining users are N=1024)
  __shared__ __bf16 As[128 * 64];   // [kk][row][32]: kk*4096 + row*32 + c
  __shared__ __bf16 Bs[128 * 64];
  const int tid = threadIdx.x;
  const int lane = tid & 63;
  const int w = tid >> 6;
  const int quad = lane >> 4, l16 = lane & 15;
  const int wr = w >> 1, wc = w & 1;

  // T1 XCD-chunked swizzle (bijective: nwg % 8 == 0 for all launches)
  const int id  = blockIdx.y * GX + blockIdx.x;
  const int nwg = GX * gridDim.y;
  const int wk  = (id & 7) * (nwg >> 3) + (id >> 3);
  const int tm = (wk / GX) * 128, tn = (wk % GX) * 128;

  f32x4 acc[4][4] = {};

  const __bf16* gA[4]; const __bf16* gB[4]; int dst[4];
#pragma unroll
  for (int j = 0; j < 4; ++j) {
    int s = w * 256 + j * 64 + lane;
    int row = (s >> 2) & 127, kk = s >> 9, c = (s & 3) * 8;
    int go = kk * 32 + c;
    gA[j] = A + (size_t)(tm + row) * Kd + go;
    gB[j] = Bt + (size_t)(tn + row) * Kd + go;
    dst[j] = s * 8;
  }

  for (int k0 = 0; k0 < Kd; k0 += 64) {
#pragma unroll
    for (int j = 0; j < 4; ++j) {
      gld_lds16(gA[j] + k0, As + dst[j]);
      gld_lds16(gB[j] + k0, Bs + dst[j]);
    }
    __syncthreads();
#pragma unroll
    for (int kk = 0; kk < 2; ++kk) {
      bf16x8 af[4], bfr[4];
#pragma unroll
      for (int t = 0; t < 4; ++t) {
        af[t]  = *(const bf16x8*)&As[kk * 4096 + (wr * 64 + t * 16 + l16) * 32 + quad * 8];
        bfr[t] = *(const bf16x8*)&Bs[kk * 4096 + (wc * 64 + t * 16 + l16) * 32 + quad * 8];
      }
#pragma unroll
      for (int mt = 0; mt < 4; ++mt)
#pragma unroll
        for (int nt = 0; nt < 4; ++nt) {
          if constexpr (SWAP)
            acc[mt][nt] = __builtin_amdgcn_mfma_f32_16x16x32_bf16(
                bfr[nt], af[mt], acc[mt][nt], 0, 0, 0);
          else
            acc[mt][nt] = __builtin_amdgcn_mfma_f32_16x16x32_bf16(
                af[mt], bfr[nt], acc[mt][nt], 0, 0, 0);
        }
    }
    __syncthreads();
  }

#pragma unroll
  for (int mt = 0; mt < 4; ++mt)
#pragma unroll
    for (int nt = 0; nt < 4; ++nt) {
      if constexpr (EPI == 2) {
        // C^T tile: row of D = out col, col of D = out row (token)
        int gm  = tm + wr * 64 + mt * 16 + l16;        // token
        int gn0 = tn + wc * 64 + nt * 16 + quad * 4;   // col base
        float4 bv = *(const float4*)&bias[gn0];
        float4 o;
        o.x = acc[mt][nt][0] + bv.x;
        o.y = acc[mt][nt][1] + bv.y;
        o.z = acc[mt][nt][2] + bv.z;
        o.w = acc[mt][nt][3] + bv.w;
        *(float4*)&((float*)Cout)[(size_t)gm * 1024 + gn0] = o;
      } else {   // EPI 1: V transposed, natural orientation
        int gm0 = tm + wr * 64 + mt * 16 + quad * 4;   // token base
        int gn  = tn + wc * 64 + nt * 16 + l16;        // feature 0..1023
        int b = gm0 >> 11, nn0 = gm0 & 2047, h = gn >> 6, d = gn & 63;
        bf16x4 o;
        o[0] = (__bf16)acc[mt][nt][0];
        o[1] = (__bf16)acc[mt][nt][1];
        o[2] = (__bf16)acc[mt][nt][2];
        o[3] = (__bf16)acc[mt][nt][3];
        __bf16* op = (__bf16*)Cout + ((size_t)(b * NH + h) * HD + d) * SEQ + nn0;
        *(bf16x4*)op = o;
      }
    }
}

// ---------------- causal flash attention, register-PV, double-buffered ----
// R11 version kept verbatim (best known: ~69.5 us; VGPR 80, no spill).
// Session conclusion: attn is issue-slot saturated (MfmaUtil 35 + VALU 44;
// dur pinned 68-70 across occupancy 18->26% and VALU cuts) -- further gains
// need a full 8-warp 32x32 rewrite, not increments.
// Grid (64, 16), one 128-row q-tile per block; xcd = bh%8 so all 16 tiles
// of a bh share one XCD's L2 (R5's verified 4.5x FETCH win); heavy/light
// tile interleave over blockIdx.y.
// Row-sum on the MATRIX pipe via ones-column MFMA (R11); St zero-init via
// loop-invariant zero C-operand.
// S^T = mfma_16x16x32(Kfrag, Qfrag): lane holds S[q=l16][k=quad*4+i] == the
// A-operand layout of mfma_f32_16x16x16_bf16 -> PV straight from registers.
// V staged with XOR swizzle; K/V double-buffered: 1 barrier/iter.
__global__ __launch_bounds__(256, 2) void attn(const __bf16* __restrict__ Q,
                                               const __bf16* __restrict__ K,
                                               const __bf16* __restrict__ Vt,
                                               __bf16* __restrict__ ctx) {
  const int tid = threadIdx.x;
  const int lane = tid & 63, w = tid >> 6;
  const int quad = lane >> 4, l16 = lane & 15;
  const int byy = blockIdx.y;                       // 0..15
  const int tile = (byy & 1) ? (15 - (byy >> 1)) : (byy >> 1);
  const int bh = blockIdx.x;                        // 0..63
  const __bf16* qb = Q + (size_t)bh * SEQ * HD;
  const __bf16* kb = K + (size_t)bh * SEQ * HD;
  const __bf16* vb = Vt + (size_t)bh * HD * SEQ;

  __shared__ __bf16 KsAll[2 * 4096];   // [buf][half*2048 + key*32 + d]
  __shared__ __bf16 VsAll[2 * 4096];   // [buf][d*64 + ((k>>3)^(d&7))*8 + (k&7)]

  const int qmin = tile * 128 + w * 32;

  // Q fragments (B-operand, scale pre-folded)
  bf16x8 aq[2][2];
#pragma unroll
  for (int qq = 0; qq < 2; ++qq)
#pragma unroll
    for (int kk = 0; kk < 2; ++kk)
      aq[qq][kk] = *(const bf16x8*)(qb + (size_t)(qmin + qq * 16 + l16) * HD +
                                    kk * 32 + quad * 8);

  f32x4 acc[2][4] = {};    // [qq][cd] rows q=quad*4+i, cols d=cd*16+l16
  f32x4 sumacc[2] = {};    // [qq] denominator: rows q=quad*4+i (ones-MFMA)
  const f32x4 fz = {};     // loop-invariant zero C-operand for St init
  const short bf16_one = (short)0x3F80;
  const short4_t vones = {bf16_one, bf16_one, bf16_one, bf16_one};

  // staging decode. K: unit u -> key r=(u>>2)&63, half h=u>>8, elem e=(u&3)*8.
  // V (swizzled): unit u -> d=u>>3, kc=(u&7)^(d&7).
  const int u0 = w * 128 + lane;
  const int u1 = u0 + 64;
  const int kOffG0 = ((u0 >> 2) & 63) * HD + (u0 >> 8) * 32 + (u0 & 3) * 8;
  const int kOffG1 = ((u1 >> 2) & 63) * HD + (u1 >> 8) * 32 + (u1 & 3) * 8;
  const int vd0 = u0 >> 3, vd1 = u1 >> 3;
  const int vOffG0 = vd0 * SEQ + (((u0 & 7) ^ (vd0 & 7)) * 8);
  const int vOffG1 = vd1 * SEQ + (((u1 & 7) ^ (vd1 & 7)) * 8);

  auto stage = [&](int k0s, int bufsel) {
    __bf16* Kb = KsAll + bufsel * 4096;
    __bf16* Vb = VsAll + bufsel * 4096;
    gld_lds16(kb + (size_t)k0s * HD + kOffG0, Kb + u0 * 8);
    gld_lds16(kb + (size_t)k0s * HD + kOffG1, Kb + u1 * 8);
    gld_lds16(vb + k0s + vOffG0, Vb + u0 * 8);
    gld_lds16(vb + k0s + vOffG1, Vb + u1 * 8);
  };

  const int nIter = 2 * tile + 2;
  stage(0, 0);

  for (int it = 0; it < nIter; ++it) {
    __syncthreads();   // buf[it&1] staged; all waves done with buf[(it+1)&1]
    if (it + 1 < nIter) stage((it + 1) * 64, (it + 1) & 1);

    const int k0 = it * 64;
    if (k0 <= qmin + 31) {   // this wave still has unmasked keys here
      const __bf16* Kb = KsAll + (it & 1) * 4096;
      const __bf16* Vb = VsAll + (it & 1) * 4096;

      bf16x8 bk[4][2];          // A-operand K frags: rows = keys
#pragma unroll
      for (int kt = 0; kt < 4; ++kt)
#pragma unroll
        for (int kk = 0; kk < 2; ++kk)
          bk[kt][kk] = *(const bf16x8*)&Kb[kk * 2048 + (kt * 16 + l16) * 32 + quad * 8];

      // V B-frags for K=16 PV: vf[kt][cd] = V[k=kt*16+quad*4 ..+3][d=cd*16+l16]
      short4_t vf[4][4];
#pragma unroll
      for (int kt = 0; kt < 4; ++kt)
#pragma unroll
        for (int cd = 0; cd < 4; ++cd)
          vf[kt][cd] = *(const short4_t*)&Vb[(cd * 16 + l16) * 64 +
                                             (((kt * 2 + (quad >> 1)) ^ (l16 & 7)) * 8) +
                                             (quad & 1) * 4];

      // S^T[k][q]: rows k = k0+kt*16+quad*4+i, cols q = qmin+qq*16+l16
      f32x4 St[4][2];
#pragma unroll
      for (int kt = 0; kt < 4; ++kt)
#pragma unroll
        for (int qq = 0; qq < 2; ++qq) {
          St[kt][qq] = __builtin_amdgcn_mfma_f32_16x16x32_bf16(
              bk[kt][0], aq[qq][0], fz, 0, 0, 0);
          St[kt][qq] = __builtin_amdgcn_mfma_f32_16x16x32_bf16(
              bk[kt][1], aq[qq][1], St[kt][qq], 0, 0, 0);
        }
      const bool full = (k0 + 63 <= qmin);
#pragma unroll
      for (int kt = 0; kt < 4; ++kt)
#pragma unroll
        for (int qq = 0; qq < 2; ++qq) {
          float e0 = __builtin_amdgcn_exp2f(St[kt][qq][0]);
          float e1 = __builtin_amdgcn_exp2f(St[kt][qq][1]);
          float e2 = __builtin_amdgcn_exp2f(St[kt][qq][2]);
          float e3 = __builtin_amdgcn_exp2f(St[kt][qq][3]);
          if (!full) {
            int kg = k0 + kt * 16 + quad * 4;
            int qg = qmin + qq * 16 + l16;
            if (kg + 0 > qg) e0 = 0.f;
            if (kg + 1 > qg) e1 = 0.f;
            if (kg + 2 > qg) e2 = 0.f;
            if (kg + 3 > qg) e3 = 0.f;
          }
          short4_t ap;
          ap[0] = __builtin_bit_cast(short, (__bf16)e0);
          ap[1] = __builtin_bit_cast(short, (__bf16)e1);
          ap[2] = __builtin_bit_cast(short, (__bf16)e2);
          ap[3] = __builtin_bit_cast(short, (__bf16)e3);
          // denominator on the matrix pipe: sum_k P[q,k] (rows q=quad*4+i)
          sumacc[qq] = __builtin_amdgcn_mfma_f32_16x16x16bf16_1k(
              ap, vones, sumacc[qq], 0, 0, 0);
          // PV straight from registers: O[q][d] tiles over d
#pragma unroll
          for (int cd = 0; cd < 4; ++cd)
            acc[qq][cd] = __builtin_amdgcn_mfma_f32_16x16x16bf16_1k(
                ap, vf[kt][cd], acc[qq][cd], 0, 0, 0);
        }
    }
  }

  const int bb = bh >> 4, hh = bh & 15;
#pragma unroll
  for (int qq = 0; qq < 2; ++qq) {
    // sumacc[qq][i] = full row sum for q = qmin+qq*16+quad*4+i (all l16 equal)
    float rinv[4];
#pragma unroll
    for (int i = 0; i < 4; ++i)
      rinv[i] = 1.0f / sumacc[qq][i];
#pragma unroll
    for (int c = 0; c < 4; ++c)
#pragma unroll
      for (int i = 0; i < 4; ++i) {
        int q = qmin + qq * 16 + quad * 4 + i;
        float o = acc[qq][c][i] * rinv[i];
        ctx[((size_t)(bb * SEQ + q)) * D_MODEL + hh * HD + c * 16 + l16] = (__bf16)o;
      }
  }
}

extern "C" void kernel_launch(void* const* d_in, const int* in_sizes, int n_in,
                              void* d_out, int out_size, void* d_ws, size_t ws_size,
                              hipStream_t stream) {
  const float* x  = (const float*)d_in[0];
  const float* Wq = (const float*)d_in[1];
  const float* Wk = (const float*)d_in[2];
  const float* Wv = (const float*)d_in[3];
  const float* Wo = (const float*)d_in[4];
  const float* bo = (const float*)d_in[5];
  float* out = (float*)d_out;
  char* ws = (char*)d_ws;
  const size_t MB = 1024 * 1024;
  __bf16* xb   = (__bf16*)(ws);             // 16 MB; reused as ctx after attn
  __bf16* Wqkv = (__bf16*)(ws + 16 * MB);   // 6 MB: Wqt|Wkt|Wvt contiguous
  __bf16* Wot  = (__bf16*)(ws + 22 * MB);   // 2 MB
  __bf16* Qh   = (__bf16*)(ws + 24 * MB);   // 16 MB [b,h,n,d], pre-scaled
  __bf16* Kh   = (__bf16*)(ws + 40 * MB);   // 16 MB [b,h,n,d]
  __bf16* Vth  = (__bf16*)(ws + 56 * MB);   // 16 MB [b,h,d,n]
  __bf16* ctx  = xb;                        // alias: xb dead after QKV GEMM

  cvt_x<<<MROWS * D_MODEL / (256 * 4), 256, 0, stream>>>(x, xb);
  cvt_wt4<<<dim3(32, 32, 4), dim3(32, 8), 0, stream>>>(Wq, Wk, Wv, Wo, Wqkv, Wot);

  // QK projection: 256^2 tile / 512 threads (R17); V projection: 128^2
  gemm256<<<dim3(8, 32), 512, 0, stream>>>(xb, Wqkv, Qh);
  gemm_bt<1><<<dim3(8, 64), 256, 0, stream>>>(xb, Wqkv + 2 * 1024 * 1024, nullptr, Vth);

  attn<<<dim3(64, 16), 256, 0, stream>>>(Qh, Kh, Vth, ctx);

  gemm_bt<2><<<dim3(8, 64), 256, 0, stream>>>(ctx, Wot, bo, out);
}